// Round 4
// baseline (7692.793 us; speedup 1.0000x reference)
//
#include <hip/hip_runtime.h>
#include <hip/hip_cooperative_groups.h>
#include <math.h>

namespace cg = cooperative_groups;

typedef _Float16 f16x8 __attribute__((ext_vector_type(8)));
typedef _Float16 f16x4 __attribute__((ext_vector_type(4)));
typedef float f32x4 __attribute__((ext_vector_type(4)));

constexpr int B_ = 4, N_ = 2048, E_ = 16384;
constexpr int D_ = 10, DM_ = 256, NH_ = 8, FE_ = 9;
constexpr int BN_ = B_ * N_;   // 8192
constexpr int BE_ = B_ * E_;   // 65536

#define DEVI __device__ __forceinline__

DEVI _Float16 f2h(float f) { return (_Float16)f; }

// ---------------- setup kernels ----------------

__global__ void init_state(const int* __restrict__ bus, const float* __restrict__ V0,
                           float* v, float* th, float* m, float* pm, float* qm,
                           int* counts) {
  int t = blockIdx.x * blockDim.x + threadIdx.x;
  if (t >= BN_) return;
  int bt = bus[t];
  pm[t] = (bt == 1) ? 0.f : 1.f;
  qm[t] = (bt == 1 || bt == 2) ? 0.f : 1.f;
  v[t] = V0[2 * t];
  th[t] = V0[2 * t + 1];
  for (int d = 0; d < D_; ++d) m[(size_t)t * D_ + d] = 0.f;
  counts[t] = 0;
}

// one pass over G,Bm: write T (row-normalized adjacency) + fp16 copies of G,Bm
__global__ __launch_bounds__(256) void build_T_cast(const float* __restrict__ G,
    const float* __restrict__ Bm, _Float16* __restrict__ Tb,
    _Float16* __restrict__ Gh, _Float16* __restrict__ Bh) {
  int row = blockIdx.x;
  int i = row & (N_ - 1);
  const float* Gr = G + (size_t)row * N_;
  const float* Br = Bm + (size_t)row * N_;
  float a[8];
  float s = 0.f;
#pragma unroll
  for (int u = 0; u < 8; ++u) {
    int j = threadIdx.x + u * 256;
    float g = Gr[j], b = Br[j];
    Gh[(size_t)row * N_ + j] = f2h(g);
    Bh[(size_t)row * N_ + j] = f2h(b);
    float av = sqrtf(g * g + b * b);
    if (j == i) av = 0.f;
    a[u] = av;
    s += av;
  }
  __shared__ float red[4];
  for (int off = 32; off; off >>= 1) s += __shfl_down(s, off);
  int lane = threadIdx.x & 63, wave = threadIdx.x >> 6;
  if (lane == 0) red[wave] = s;
  __syncthreads();
  float tot = red[0] + red[1] + red[2] + red[3];
  float inv = 1.f / fmaxf(tot, 1e-12f);
#pragma unroll
  for (int u = 0; u < 8; ++u) {
    int j = threadIdx.x + u * 256;
    Tb[(size_t)row * N_ + j] = f2h(a[u] * inv);
  }
}

// fp32 fallback (no Gh/Bh)
__global__ __launch_bounds__(256) void build_T(const float* __restrict__ G,
    const float* __restrict__ Bm, _Float16* __restrict__ Tb) {
  int row = blockIdx.x;
  int i = row & (N_ - 1);
  const float* Gr = G + (size_t)row * N_;
  const float* Br = Bm + (size_t)row * N_;
  float a[8];
  float s = 0.f;
#pragma unroll
  for (int u = 0; u < 8; ++u) {
    int j = threadIdx.x + u * 256;
    float g = Gr[j], b = Br[j];
    float av = sqrtf(g * g + b * b);
    if (j == i) av = 0.f;
    a[u] = av;
    s += av;
  }
  __shared__ float red[4];
  for (int off = 32; off; off >>= 1) s += __shfl_down(s, off);
  int lane = threadIdx.x & 63, wave = threadIdx.x >> 6;
  if (lane == 0) red[wave] = s;
  __syncthreads();
  float tot = red[0] + red[1] + red[2] + red[3];
  float inv = 1.f / fmaxf(tot, 1e-12f);
#pragma unroll
  for (int u = 0; u < 8; ++u) {
    int j = threadIdx.x + u * 256;
    Tb[(size_t)row * N_ + j] = f2h(a[u] * inv);
  }
}

__global__ void edge_prep(const int* __restrict__ ei, const float* __restrict__ efeat,
    const float* __restrict__ We, const float* __restrict__ be,
    float* __restrict__ eb, int* __restrict__ srcf, int* __restrict__ dstf,
    int* __restrict__ counts) {
  int t = blockIdx.x * blockDim.x + threadIdx.x;
  if (t >= BE_) return;
  int b = t / E_, e = t - b * E_;
  int src = ei[(size_t)b * 2 * E_ + e];
  int dst = ei[(size_t)b * 2 * E_ + E_ + e];
  srcf[t] = src + b * N_;
  int df = dst + b * N_;
  dstf[t] = df;
  atomicAdd(&counts[df], 1);
  float fv[FE_];
#pragma unroll
  for (int f = 0; f < FE_; ++f) fv[f] = efeat[(size_t)t * FE_ + f];
#pragma unroll
  for (int h = 0; h < NH_; ++h) {
    float s = be[h];
#pragma unroll
    for (int f = 0; f < FE_; ++f) s += fv[f] * We[f * NH_ + h];
    eb[(size_t)t * NH_ + h] = s;
  }
}

__global__ void scan_kernel(const int* __restrict__ counts, int* __restrict__ offs,
                            int* __restrict__ cursor) {
  __shared__ int part[256];
  int t = threadIdx.x;
  int base = t * 32;
  int loc[32];
  int s = 0;
#pragma unroll
  for (int i = 0; i < 32; ++i) { loc[i] = counts[base + i]; s += loc[i]; }
  part[t] = s;
  __syncthreads();
  for (int off = 1; off < 256; off <<= 1) {
    int vv = (t >= off) ? part[t - off] : 0;
    __syncthreads();
    part[t] += vv;
    __syncthreads();
  }
  int run = part[t] - s;
#pragma unroll
  for (int i = 0; i < 32; ++i) {
    offs[base + i] = run;
    cursor[base + i] = run;
    run += loc[i];
  }
  if (t == 255) offs[BN_] = run;
}

__global__ void scatter_kernel(const int* __restrict__ dstf, int* cursor,
                               int* __restrict__ perm) {
  int t = blockIdx.x * blockDim.x + threadIdx.x;
  if (t >= BE_) return;
  int d = dstf[t];
  int pos = atomicAdd(&cursor[d], 1);
  perm[pos] = t;
}

// remove one indirection for attention: sp[j]=srcf[perm[j]], ebp[j]=eb[perm[j]]
__global__ void edge_reorder(const int* __restrict__ perm, const int* __restrict__ srcf,
                             const float* __restrict__ eb, int* __restrict__ sp,
                             float* __restrict__ ebp) {
  int j = blockIdx.x * 256 + threadIdx.x;
  if (j >= BE_) return;
  int e = perm[j];
  sp[j] = srcf[e];
#pragma unroll
  for (int h = 0; h < NH_; ++h) ebp[(size_t)j * 8 + h] = eb[(size_t)e * 8 + h];
}

__global__ void prep_weights(const float* Wq, const float* bq, const float* Wk,
    const float* bk, const float* Wv, const float* bvv, const float* Wo,
    const float* Wf1, const float* Wf2, const float* Wth, const float* bth,
    const float* Wvh, const float* bvh, const float* Wm, const float* bm,
    const float* Win,
    _Float16* Wqkvt, float* bqkv, _Float16* Wot,
    _Float16* Wf1t, _Float16* Wf2t, float* Wheads, float* bheads,
    _Float16* Wint) {
  int i = blockIdx.x * blockDim.x + threadIdx.x;
  if (i < 768 * 256) {
    int n = i >> 8, kk = i & 255;
    float val = n < 256 ? Wq[kk * 256 + n]
              : n < 512 ? Wk[kk * 256 + (n - 256)] : Wv[kk * 256 + (n - 512)];
    Wqkvt[n * 256 + kk] = f2h(val);
    return;
  }
  i -= 768 * 256;
  if (i < 256 * 256) {
    int n = i >> 8, kk = i & 255;
    Wot[n * 256 + kk] = f2h(Wo[kk * 256 + n]);
    return;
  }
  i -= 256 * 256;
  if (i < 1024 * 256) {
    int n = i >> 8, kk = i & 255;
    Wf1t[n * 256 + kk] = f2h(Wf1[kk * 1024 + n]);
    return;
  }
  i -= 1024 * 256;
  if (i < 256 * 1024) {
    int n = i >> 10, kk = i & 1023;
    Wf2t[n * 1024 + kk] = f2h(Wf2[kk * 256 + n]);
    return;
  }
  i -= 256 * 1024;
  if (i < 30 * 3072) {
    int k = i / 3072, j = i - k * 3072;
    int row = j / 12, o = j - row * 12;
    float val = o == 0 ? Wth[k * 256 + row]
              : o == 1 ? Wvh[k * 256 + row] : Wm[k * 2560 + row * 10 + (o - 2)];
    Wheads[k * 3072 + j] = val;
    return;
  }
  i -= 30 * 3072;
  if (i < 360) {
    int k = i / 12, o = i - k * 12;
    bheads[i] = o == 0 ? bth[k] : o == 1 ? bvh[k] : bm[k * 10 + (o - 2)];
    return;
  }
  i -= 360;
  if (i < 768) {
    bqkv[i] = i < 256 ? bq[i] : i < 512 ? bk[i - 256] : bvv[i - 512];
    return;
  }
  i -= 768;
  if (i < 256 * 32) {
    int n = i >> 5, kk = i & 31;
    Wint[n * 32 + kk] = (kk < 28) ? f2h(Win[kk * 256 + n]) : (_Float16)0.f;
  }
}

// ---------------- per-step kernels ----------------

DEVI void ns_epilogue(int b, int row, float sre, float sim, int lane,
                      const float2* sef, const float* v, const float* th,
                      const float* P, const float* Q, const float* pm,
                      const float* qm, const float* m, _Float16* nsT) {
  for (int off = 1; off < 64; off <<= 1) {
    sre += __shfl_xor(sre, off);
    sim += __shfl_xor(sim, off);
  }
  if (lane < 16) {
    int node = b * N_ + row;
    float val;
    if (lane == 0) val = v[node];
    else if (lane == 1) val = th[node];
    else if (lane == 2) {
      float2 ef = sef[row];
      val = (P[node] - (ef.x * sre + ef.y * sim)) * pm[node];
    } else if (lane == 3) {
      float2 ef = sef[row];
      val = (Q[node] - (ef.y * sre - ef.x * sim)) * qm[node];
    } else if (lane < 14) val = m[(size_t)node * 10 + (lane - 4)];
    else val = 0.f;
    nsT[(size_t)b * 16 * N_ + (size_t)lane * N_ + row] = f2h(val);
  }
}

__global__ __launch_bounds__(256) void matvec_ns_f16(const _Float16* __restrict__ Gh,
    const _Float16* __restrict__ Bh, const float* __restrict__ v,
    const float* __restrict__ th, const float* __restrict__ P,
    const float* __restrict__ Q, const float* __restrict__ pm,
    const float* __restrict__ qm, const float* __restrict__ m,
    _Float16* __restrict__ nsT) {
  int b = blockIdx.y;
  __shared__ float2 sef[N_];
  for (int i = threadIdx.x; i < N_; i += 256) {
    float vv = v[b * N_ + i], tt = th[b * N_ + i];
    float sn, cs;
    __sincosf(tt, &sn, &cs);
    sef[i] = make_float2(vv * cs, vv * sn);
  }
  __syncthreads();
  int wave = threadIdx.x >> 6, lane = threadIdx.x & 63;
  for (int rr = 0; rr < 4; ++rr) {
    int row = blockIdx.x * 16 + wave * 4 + rr;
    const _Float16* Gr = Gh + ((size_t)b * N_ + row) * N_;
    const _Float16* Br = Bh + ((size_t)b * N_ + row) * N_;
    float sre = 0.f, sim = 0.f;
#pragma unroll
    for (int jj = 0; jj < 4; ++jj) {
      int j = lane * 8 + jj * 512;
      f16x8 g8 = *(const f16x8*)(Gr + j);
      f16x8 b8 = *(const f16x8*)(Br + j);
#pragma unroll
      for (int u = 0; u < 8; ++u) {
        float g = (float)g8[u], bb = (float)b8[u];
        float2 ef = sef[j + u];
        sre += g * ef.x - bb * ef.y;
        sim += g * ef.y + bb * ef.x;
      }
    }
    ns_epilogue(b, row, sre, sim, lane, sef, v, th, P, Q, pm, qm, m, nsT);
  }
}

__global__ __launch_bounds__(256) void matvec_ns_f32(const float* __restrict__ G,
    const float* __restrict__ Bm, const float* __restrict__ v,
    const float* __restrict__ th, const float* __restrict__ P,
    const float* __restrict__ Q, const float* __restrict__ pm,
    const float* __restrict__ qm, const float* __restrict__ m,
    _Float16* __restrict__ nsT) {
  int b = blockIdx.y;
  __shared__ float2 sef[N_];
  for (int i = threadIdx.x; i < N_; i += 256) {
    float vv = v[b * N_ + i], tt = th[b * N_ + i];
    float sn, cs;
    __sincosf(tt, &sn, &cs);
    sef[i] = make_float2(vv * cs, vv * sn);
  }
  __syncthreads();
  int wave = threadIdx.x >> 6, lane = threadIdx.x & 63;
  for (int rr = 0; rr < 4; ++rr) {
    int row = blockIdx.x * 16 + wave * 4 + rr;
    const float* Gr = G + ((size_t)b * N_ + row) * N_;
    const float* Br = Bm + ((size_t)b * N_ + row) * N_;
    float sre = 0.f, sim = 0.f;
#pragma unroll
    for (int jj = 0; jj < 8; ++jj) {
      int j = lane * 4 + jj * 256;
      float4 g4 = *(const float4*)(Gr + j);
      float4 b4 = *(const float4*)(Br + j);
      float2 e0 = sef[j], e1 = sef[j + 1], e2 = sef[j + 2], e3 = sef[j + 3];
      sre += g4.x * e0.x - b4.x * e0.y + g4.y * e1.x - b4.y * e1.y
           + g4.z * e2.x - b4.z * e2.y + g4.w * e3.x - b4.w * e3.y;
      sim += g4.x * e0.y + b4.x * e0.x + g4.y * e1.y + b4.y * e1.x
           + g4.z * e2.y + b4.z * e2.x + g4.w * e3.y + b4.w * e3.x;
    }
    ns_epilogue(b, row, sre, sim, lane, sef, v, th, P, Q, pm, qm, m, nsT);
  }
}

// one 16-node x 16-channel tile of Hout^T = (T @ Hin)^T; returns this thread's
// value for channel (tid>>4), node (tid&15)
DEVI float khop_tile(const _Float16* __restrict__ Tb, const _Float16* __restrict__ Hin,
                     int b, int m0, int wave, int lm, int lq, int tid,
                     float (*red)[16][17]) {
  f32x4 acc = {0.f, 0.f, 0.f, 0.f};
  const _Float16* Trow = Tb + ((size_t)b * N_ + m0 + lm) * N_ + wave * 512 + lq * 8;
  const _Float16* Hrow = Hin + ((size_t)b * 16 + lm) * N_ + wave * 512 + lq * 8;
#pragma unroll 4
  for (int k = 0; k < 512; k += 32) {
    f16x8 a = *(const f16x8*)(Trow + k);
    f16x8 hb = *(const f16x8*)(Hrow + k);
    acc = __builtin_amdgcn_mfma_f32_16x16x32_f16(a, hb, acc, 0, 0, 0);
  }
#pragma unroll
  for (int r = 0; r < 4; ++r) red[wave][lq * 4 + r][lm] = acc[r];
  __syncthreads();
  int c = tid >> 4, rr = tid & 15;
  float s = red[0][rr][c] + red[1][rr][c] + red[2][rr][c] + red[3][rr][c];
  __syncthreads();
  return s;
}

// cooperative: all 3 hops + input projection in one launch (grid 128x4, 256 thr)
__global__ __launch_bounds__(256) void khop_chain(
    const _Float16* __restrict__ Tb, const _Float16* __restrict__ nsT,
    _Float16* __restrict__ H1, _Float16* __restrict__ H2,
    const _Float16* __restrict__ Wint, const float* __restrict__ bin,
    float hw0, float hw1, float hw2,
    float* __restrict__ x0, _Float16* __restrict__ xh) {
  cg::grid_group grid = cg::this_grid();
  int b = blockIdx.y, m0 = blockIdx.x * 16;
  int tid = threadIdx.x;
  int wave = tid >> 6, lane = tid & 63;
  int lm = lane & 15, lq = lane >> 4;
  __shared__ float red[4][16][17];
  __shared__ _Float16 in28s[16][32];
  int oc = tid >> 4, orr = tid & 15;
  size_t oidx = ((size_t)b * 16 + oc) * N_ + m0 + orr;

  float s = khop_tile(Tb, nsT, b, m0, wave, lm, lq, tid, red);
  float accv = hw0 * s;
  H1[oidx] = f2h(s);
  grid.sync();
  s = khop_tile(Tb, H1, b, m0, wave, lm, lq, tid, red);
  accv += hw1 * s;
  H2[oidx] = f2h(s);
  grid.sync();
  s = khop_tile(Tb, H2, b, m0, wave, lm, lq, tid, red);
  accv += hw2 * s;

  if (oc < 14) {
    in28s[orr][oc] = nsT[oidx];
    in28s[orr][14 + oc] = f2h(accv);
  } else if (oc == 14) {
    in28s[orr][28] = (_Float16)0.f;
    in28s[orr][29] = (_Float16)0.f;
  } else {
    in28s[orr][30] = (_Float16)0.f;
    in28s[orr][31] = (_Float16)0.f;
  }
  __syncthreads();
  f16x8 afrag = *(const f16x8*)(&in28s[lm][lq * 8]);
#pragma unroll
  for (int nt = 0; nt < 4; ++nt) {
    int n0 = wave * 64 + nt * 16;
    f16x8 bfrag = *(const f16x8*)(Wint + (size_t)(n0 + lm) * 32 + lq * 8);
    f32x4 c4 = {0.f, 0.f, 0.f, 0.f};
    c4 = __builtin_amdgcn_mfma_f32_16x16x32_f16(afrag, bfrag, c4, 0, 0, 0);
    float bv = bin[n0 + lm];
#pragma unroll
    for (int rg = 0; rg < 4; ++rg) {
      int rw = lq * 4 + rg;
      float val = c4[rg] + bv;
      size_t o = ((size_t)(b * N_ + m0 + rw)) * 256 + n0 + lm;
      x0[o] = val;
      xh[o] = f2h(val);
    }
  }
}

// generic C(M,N) = A @ Wt^T + bias (used for QKV)
__global__ __launch_bounds__(256) void gemm_kernel(const _Float16* __restrict__ A,
    const _Float16* __restrict__ Wt, const float* __restrict__ bias,
    float* __restrict__ Cf, _Float16* __restrict__ Ch,
    int N, int K, int relu) {
  int wave = threadIdx.x >> 6, lane = threadIdx.x & 63;
  int wy = wave >> 1, wx = wave & 1;
  int m0 = blockIdx.x * 64 + wy * 32;
  int n0 = blockIdx.y * 64 + wx * 32;
  int lm = lane & 15, lq = lane >> 4;
  f32x4 acc[2][2] = {};
  const _Float16* A0 = A + (size_t)(m0 + lm) * K + lq * 8;
  const _Float16* A1 = A0 + (size_t)16 * K;
  const _Float16* B0 = Wt + (size_t)(n0 + lm) * K + lq * 8;
  const _Float16* B1 = B0 + (size_t)16 * K;
  for (int k = 0; k < K; k += 32) {
    f16x8 a0 = *(const f16x8*)(A0 + k);
    f16x8 a1 = *(const f16x8*)(A1 + k);
    f16x8 b0 = *(const f16x8*)(B0 + k);
    f16x8 b1 = *(const f16x8*)(B1 + k);
    acc[0][0] = __builtin_amdgcn_mfma_f32_16x16x32_f16(a0, b0, acc[0][0], 0, 0, 0);
    acc[0][1] = __builtin_amdgcn_mfma_f32_16x16x32_f16(a0, b1, acc[0][1], 0, 0, 0);
    acc[1][0] = __builtin_amdgcn_mfma_f32_16x16x32_f16(a1, b0, acc[1][0], 0, 0, 0);
    acc[1][1] = __builtin_amdgcn_mfma_f32_16x16x32_f16(a1, b1, acc[1][1], 0, 0, 0);
  }
#pragma unroll
  for (int tm = 0; tm < 2; ++tm)
#pragma unroll
    for (int tn = 0; tn < 2; ++tn) {
      int col = n0 + tn * 16 + lm;
      float bvv = bias ? bias[col] : 0.f;
#pragma unroll
      for (int r = 0; r < 4; ++r) {
        int row = m0 + tm * 16 + lq * 4 + r;
        float val = acc[tm][tn][r] + bvv;
        if (relu) val = fmaxf(val, 0.f);
        size_t o = (size_t)row * N + col;
        if (Cf) Cf[o] = val;
        if (Ch) Ch[o] = f2h(val);
      }
    }
}

// one wave per node; software-pipelined edge gather
__global__ __launch_bounds__(256) void attn_kernel(const _Float16* __restrict__ qkv,
    const int* __restrict__ offs, const int* __restrict__ sp,
    const float* __restrict__ ebp, _Float16* __restrict__ aggh) {
  int node = blockIdx.x * 4 + (threadIdx.x >> 6);
  int lane = threadIdx.x & 63;
  int h = lane >> 3;
  f16x4 qh = *(const f16x4*)(qkv + (size_t)node * 768 + lane * 4);
  float4 q4 = {(float)qh[0], (float)qh[1], (float)qh[2], (float)qh[3]};
  int beg = offs[node], end = offs[node + 1];
  float mx = -3.0e38f, den = 0.f;
  float4 acc = {0.f, 0.f, 0.f, 0.f};
  f16x4 kh_n = {}, vh_n = {};
  float eb_n = 0.f;
  if (beg < end) {
    int s = sp[beg];
    const _Float16* base = qkv + (size_t)s * 768 + lane * 4;
    kh_n = *(const f16x4*)(base + 256);
    vh_n = *(const f16x4*)(base + 512);
    eb_n = ebp[(size_t)beg * 8 + h];
  }
  for (int j = beg; j < end; ++j) {
    f16x4 kh = kh_n, vh = vh_n;
    float ebv = eb_n;
    if (j + 1 < end) {
      int s2 = sp[j + 1];
      const _Float16* b2 = qkv + (size_t)s2 * 768 + lane * 4;
      kh_n = *(const f16x4*)(b2 + 256);
      vh_n = *(const f16x4*)(b2 + 512);
      eb_n = ebp[(size_t)(j + 1) * 8 + h];
    }
    float p = q4.x * (float)kh[0] + q4.y * (float)kh[1]
            + q4.z * (float)kh[2] + q4.w * (float)kh[3];
    p += __shfl_xor(p, 1);
    p += __shfl_xor(p, 2);
    p += __shfl_xor(p, 4);
    float score = p * 0.17677669529663687f + ebv;
    float nm = fmaxf(mx, score);
    float sc = __expf(mx - nm);
    float w = __expf(score - nm);
    den = den * sc + w;
    acc.x = acc.x * sc + w * (float)vh[0];
    acc.y = acc.y * sc + w * (float)vh[1];
    acc.z = acc.z * sc + w * (float)vh[2];
    acc.w = acc.w * sc + w * (float)vh[3];
    mx = nm;
  }
  float inv = den > 0.f ? 1.f / den : 0.f;
  f16x4 o;
  o[0] = f2h(acc.x * inv);
  o[1] = f2h(acc.y * inv);
  o[2] = f2h(acc.z * inv);
  o[3] = f2h(acc.w * inv);
  *(f16x4*)(aggh + (size_t)node * DM_ + lane * 4) = o;
}

// O-proj + residual + LN1 (M-tile 16, grid 512 blocks)
__global__ __launch_bounds__(256) void oproj_ln1(const _Float16* __restrict__ A,
    const _Float16* __restrict__ Wt, const float* __restrict__ bias,
    const float* __restrict__ res, const float* __restrict__ g,
    const float* __restrict__ bb, float* __restrict__ yF,
    _Float16* __restrict__ yH) {
  int m0 = blockIdx.x * 16;
  int wave = threadIdx.x >> 6, lane = threadIdx.x & 63;
  int lm = lane & 15, lq = lane >> 4;
  int n0 = wave * 64;
  f32x4 acc[4] = {};
  const _Float16* Ap = A + (size_t)(m0 + lm) * 256 + lq * 8;
  const _Float16* Bp = Wt + (size_t)(n0 + lm) * 256 + lq * 8;
  for (int k = 0; k < 256; k += 32) {
    f16x8 a0 = *(const f16x8*)(Ap + k);
#pragma unroll
    for (int nt = 0; nt < 4; ++nt) {
      f16x8 bf = *(const f16x8*)(Bp + nt * 16 * 256 + k);
      acc[nt] = __builtin_amdgcn_mfma_f32_16x16x32_f16(a0, bf, acc[nt], 0, 0, 0);
    }
  }
  float val[4][4];
  float rsum[4] = {}, rsq[4] = {};
#pragma unroll
  for (int nt = 0; nt < 4; ++nt) {
    int col = n0 + nt * 16 + lm;
    float bv = bias[col];
#pragma unroll
    for (int rg = 0; rg < 4; ++rg) {
      int row = m0 + lq * 4 + rg;
      float x = acc[nt][rg] + bv + res[(size_t)row * 256 + col];
      val[nt][rg] = x;
      rsum[rg] += x;
      rsq[rg] += x * x;
    }
  }
#pragma unroll
  for (int rg = 0; rg < 4; ++rg)
    for (int off = 1; off < 16; off <<= 1) {
      rsum[rg] += __shfl_xor(rsum[rg], off);
      rsq[rg] += __shfl_xor(rsq[rg], off);
    }
  __shared__ float redS[16][4], redQ[16][4];
  if (lm == 0) {
#pragma unroll
    for (int rg = 0; rg < 4; ++rg) {
      int r = lq * 4 + rg;
      redS[r][wave] = rsum[rg];
      redQ[r][wave] = rsq[rg];
    }
  }
  __syncthreads();
#pragma unroll
  for (int rg = 0; rg < 4; ++rg) {
    int r = lq * 4 + rg;
    float tS = redS[r][0] + redS[r][1] + redS[r][2] + redS[r][3];
    float tQ = redQ[r][0] + redQ[r][1] + redQ[r][2] + redQ[r][3];
    float mu = tS * (1.f / 256.f);
    float var = tQ * (1.f / 256.f) - mu * mu;
    float rs = rsqrtf(var + 1e-5f);
    int row = m0 + r;
#pragma unroll
    for (int nt = 0; nt < 4; ++nt) {
      int col = n0 + nt * 16 + lm;
      float y = g[col] * (val[nt][rg] - mu) * rs + bb[col];
      size_t o = (size_t)row * 256 + col;
      yF[o] = y;
      yH[o] = f2h(y);
    }
  }
}

// fused FFN: h=relu(x@Wf1+b) in LDS, y=h@Wf2+b, +res, LN2, heads, state update
__global__ __launch_bounds__(512) void ffn_fused(const _Float16* __restrict__ A,
    const _Float16* __restrict__ Wf1t, const float* __restrict__ bf1,
    const _Float16* __restrict__ Wf2t, const float* __restrict__ bf2,
    const float* __restrict__ res, const float* __restrict__ g,
    const float* __restrict__ bb, const float* __restrict__ Wh,
    const float* __restrict__ bh, const float* __restrict__ pm,
    const float* __restrict__ qm, float* __restrict__ v,
    float* __restrict__ th, float* __restrict__ m) {
  constexpr int HP = 1032;  // stride ≡ 4 mod 32 banks → 2-way (free)
  int m0 = blockIdx.x * 32;
  int tid = threadIdx.x;
  int wave = tid >> 6, lane = tid & 63;
  int lm = lane & 15, lq = lane >> 4;
  __shared__ _Float16 hs[32][HP];
  __shared__ float xs[32][261];   // odd stride → conflict-free column reads
  __shared__ float whs[3072];
  __shared__ float part[32][193]; // odd stride → conflict-free row reads
  __shared__ float redS[32][8], redQ[32][8];
  for (int i = tid; i < 3072; i += 512) whs[i] = Wh[i];
  // phase 1: h[32][1024] = relu(x @ Wf1 + bf1)
  {
    int n0 = wave * 128;
    f32x4 acc1[2][8] = {};
    const _Float16* Ap = A + (size_t)(m0 + lm) * 256 + lq * 8;
    const _Float16* Bp = Wf1t + (size_t)(n0 + lm) * 256 + lq * 8;
    for (int k = 0; k < 256; k += 32) {
      f16x8 a0 = *(const f16x8*)(Ap + k);
      f16x8 a1 = *(const f16x8*)(Ap + 16 * 256 + k);
#pragma unroll
      for (int nt = 0; nt < 8; ++nt) {
        f16x8 bf = *(const f16x8*)(Bp + nt * 16 * 256 + k);
        acc1[0][nt] = __builtin_amdgcn_mfma_f32_16x16x32_f16(a0, bf, acc1[0][nt], 0, 0, 0);
        acc1[1][nt] = __builtin_amdgcn_mfma_f32_16x16x32_f16(a1, bf, acc1[1][nt], 0, 0, 0);
      }
    }
#pragma unroll
    for (int mt = 0; mt < 2; ++mt)
#pragma unroll
      for (int nt = 0; nt < 8; ++nt) {
        int col = n0 + nt * 16 + lm;
        float bv = bf1[col];
#pragma unroll
        for (int rg = 0; rg < 4; ++rg) {
          int rloc = mt * 16 + lq * 4 + rg;
          hs[rloc][col] = f2h(fmaxf(acc1[mt][nt][rg] + bv, 0.f));
        }
      }
  }
  __syncthreads();
  // phase 2: y[32][256] = h @ Wf2 + bf2 + res, LN
  float val[2][2][4];
  float rsum[2][4] = {}, rsq[2][4] = {};
  {
    int n0 = wave * 32;
    f32x4 acc2[2][2] = {};
    const _Float16* Bp = Wf2t + (size_t)(n0 + lm) * 1024 + lq * 8;
    for (int k = 0; k < 1024; k += 32) {
      f16x8 a0 = *(const f16x8*)(&hs[lm][k + lq * 8]);
      f16x8 a1 = *(const f16x8*)(&hs[16 + lm][k + lq * 8]);
      f16x8 b0 = *(const f16x8*)(Bp + k);
      f16x8 b1 = *(const f16x8*)(Bp + 16 * 1024 + k);
      acc2[0][0] = __builtin_amdgcn_mfma_f32_16x16x32_f16(a0, b0, acc2[0][0], 0, 0, 0);
      acc2[0][1] = __builtin_amdgcn_mfma_f32_16x16x32_f16(a0, b1, acc2[0][1], 0, 0, 0);
      acc2[1][0] = __builtin_amdgcn_mfma_f32_16x16x32_f16(a1, b0, acc2[1][0], 0, 0, 0);
      acc2[1][1] = __builtin_amdgcn_mfma_f32_16x16x32_f16(a1, b1, acc2[1][1], 0, 0, 0);
    }
#pragma unroll
    for (int mt = 0; mt < 2; ++mt)
#pragma unroll
      for (int nt = 0; nt < 2; ++nt) {
        int col = n0 + nt * 16 + lm;
        float bv = bf2[col];
#pragma unroll
        for (int rg = 0; rg < 4; ++rg) {
          int row = m0 + mt * 16 + lq * 4 + rg;
          float x = acc2[mt][nt][rg] + bv + res[(size_t)row * 256 + col];
          val[mt][nt][rg] = x;
          rsum[mt][rg] += x;
          rsq[mt][rg] += x * x;
        }
      }
  }
#pragma unroll
  for (int mt = 0; mt < 2; ++mt)
#pragma unroll
    for (int rg = 0; rg < 4; ++rg)
      for (int off = 1; off < 16; off <<= 1) {
        rsum[mt][rg] += __shfl_xor(rsum[mt][rg], off);
        rsq[mt][rg] += __shfl_xor(rsq[mt][rg], off);
      }
  if (lm == 0) {
#pragma unroll
    for (int mt = 0; mt < 2; ++mt)
#pragma unroll
      for (int rg = 0; rg < 4; ++rg) {
        int r = mt * 16 + lq * 4 + rg;
        redS[r][wave] = rsum[mt][rg];
        redQ[r][wave] = rsq[mt][rg];
      }
  }
  __syncthreads();
#pragma unroll
  for (int mt = 0; mt < 2; ++mt)
#pragma unroll
    for (int rg = 0; rg < 4; ++rg) {
      int r = mt * 16 + lq * 4 + rg;
      float tS = 0.f, tQ = 0.f;
#pragma unroll
      for (int w = 0; w < 8; ++w) { tS += redS[r][w]; tQ += redQ[r][w]; }
      float mu = tS * (1.f / 256.f);
      float var = tQ * (1.f / 256.f) - mu * mu;
      float rs = rsqrtf(var + 1e-5f);
#pragma unroll
      for (int nt = 0; nt < 2; ++nt) {
        int col = wave * 32 + nt * 16 + lm;
        xs[r][col] = g[col] * (val[mt][nt][rg] - mu) * rs + bb[col];
      }
    }
  __syncthreads();
  // heads: 12 dots per row over 256 cols (16 groups x 16 cols)
  {
    int rw = tid & 31, grp = tid >> 5;
    float pa[12] = {};
    for (int c = 0; c < 16; ++c) {
      int col = grp * 16 + c;
      float xv = xs[rw][col];
#pragma unroll
      for (int o = 0; o < 12; ++o) pa[o] += xv * whs[col * 12 + o];
    }
#pragma unroll
    for (int o = 0; o < 12; ++o) part[rw][grp * 12 + o] = pa[o];
  }
  __syncthreads();
  if (tid < 32) {
    int node = m0 + tid;
    float tot[12];
#pragma unroll
    for (int o = 0; o < 12; ++o) {
      float s = bh[o];
#pragma unroll
      for (int grp = 0; grp < 16; ++grp) s += part[tid][grp * 12 + o];
      tot[o] = s;
    }
    th[node] += tot[0] * pm[node];
    v[node] += tot[1] * qm[node];
#pragma unroll
    for (int d = 0; d < 10; ++d) m[(size_t)node * 10 + d] = tot[2 + d];
  }
}

__global__ void out_kernel(const float* __restrict__ v, const float* __restrict__ th,
                           float* __restrict__ out) {
  int t = blockIdx.x * blockDim.x + threadIdx.x;
  if (t >= BN_) return;
  out[2 * t] = v[t];
  out[2 * t + 1] = th[t];
}

// ---------------- launcher ----------------

extern "C" void kernel_launch(void* const* d_in, const int* in_sizes, int n_in,
                              void* d_out, int out_size, void* d_ws, size_t ws_size,
                              hipStream_t stream) {
  const int* bus = (const int*)d_in[0];
  const int* ei = (const int*)d_in[1];
  const float* G = (const float*)d_in[2];
  const float* Bm = (const float*)d_in[3];
  const float* P = (const float*)d_in[4];
  const float* Q = (const float*)d_in[5];
  const float* V0 = (const float*)d_in[6];
  const float* efeat = (const float*)d_in[7];
  const float* Win = (const float*)d_in[8];
  const float* bin = (const float*)d_in[9];
  const float* Wq = (const float*)d_in[10];
  const float* bq = (const float*)d_in[11];
  const float* Wk = (const float*)d_in[12];
  const float* bk = (const float*)d_in[13];
  const float* Wv = (const float*)d_in[14];
  const float* bv = (const float*)d_in[15];
  const float* Wo = (const float*)d_in[16];
  const float* bo = (const float*)d_in[17];
  const float* We = (const float*)d_in[18];
  const float* be = (const float*)d_in[19];
  const float* g1 = (const float*)d_in[20];
  const float* b1 = (const float*)d_in[21];
  const float* g2 = (const float*)d_in[22];
  const float* b2 = (const float*)d_in[23];
  const float* Wf1 = (const float*)d_in[24];
  const float* bf1 = (const float*)d_in[25];
  const float* Wf2 = (const float*)d_in[26];
  const float* bf2 = (const float*)d_in[27];
  const float* Wth = (const float*)d_in[28];
  const float* bth = (const float*)d_in[29];
  const float* Wvh = (const float*)d_in[30];
  const float* bvh = (const float*)d_in[31];
  const float* Wm = (const float*)d_in[32];
  const float* bm = (const float*)d_in[33];
  float* out = (float*)d_out;

  char* p = (char*)d_ws;
  auto alloc = [&](size_t bytes) -> void* {
    void* r = (void*)p;
    p += (bytes + 255) & ~(size_t)255;
    return r;
  };
  _Float16* Tb = (_Float16*)alloc((size_t)BN_ * N_ * 2);
  _Float16* nsT = (_Float16*)alloc((size_t)B_ * 16 * N_ * 2);
  _Float16* H1 = (_Float16*)alloc((size_t)B_ * 16 * N_ * 2);
  _Float16* H2 = (_Float16*)alloc((size_t)B_ * 16 * N_ * 2);
  _Float16* qkvh = (_Float16*)alloc((size_t)BN_ * 768 * 2);
  float* x0 = (float*)alloc((size_t)BN_ * 256 * 4);
  float* x1 = (float*)alloc((size_t)BN_ * 256 * 4);
  _Float16* xhA = (_Float16*)alloc((size_t)BN_ * 256 * 2);
  _Float16* xhB = (_Float16*)alloc((size_t)BN_ * 256 * 2);
  float* eb = (float*)alloc((size_t)BE_ * 8 * 4);
  float* ebp = (float*)alloc((size_t)BE_ * 8 * 4);
  int* srcf = (int*)alloc((size_t)BE_ * 4);
  int* dstf = (int*)alloc((size_t)BE_ * 4);
  int* sp = (int*)alloc((size_t)BE_ * 4);
  int* counts = (int*)alloc((size_t)BN_ * 4);
  int* offs = (int*)alloc((size_t)(BN_ + 1) * 4);
  int* cursor = (int*)alloc((size_t)BN_ * 4);
  int* perm = (int*)alloc((size_t)BE_ * 4);
  _Float16* Wqkvt = (_Float16*)alloc(768 * 256 * 2);
  _Float16* Wot = (_Float16*)alloc(256 * 256 * 2);
  _Float16* Wf1t = (_Float16*)alloc(1024 * 256 * 2);
  _Float16* Wf2t = (_Float16*)alloc(256 * 1024 * 2);
  _Float16* Wint = (_Float16*)alloc(256 * 32 * 2);
  float* Wheads = (float*)alloc(30 * 3072 * 4);
  float* bheads = (float*)alloc(30 * 12 * 4);
  float* bqkv = (float*)alloc(768 * 4);
  float* v = (float*)alloc((size_t)BN_ * 4);
  float* th = (float*)alloc((size_t)BN_ * 4);
  float* pm = (float*)alloc((size_t)BN_ * 4);
  float* qm = (float*)alloc((size_t)BN_ * 4);
  float* m = (float*)alloc((size_t)BN_ * 10 * 4);

  size_t gb_bytes = (size_t)B_ * N_ * N_ * 2;
  size_t used = (size_t)(p - (char*)d_ws);
  bool f16gb = (used + 2 * (gb_bytes + 256) <= ws_size);
  _Float16* Gh = nullptr;
  _Float16* Bh = nullptr;
  if (f16gb) {
    Gh = (_Float16*)alloc(gb_bytes);
    Bh = (_Float16*)alloc(gb_bytes);
  }

  double hwd[3], z = 0.0;
  for (int i = 0; i < 3; ++i) {
    hwd[i] = exp(-((double)(i + 1) * (i + 1)) / (2.0 * 1.5 * 1.5));
    z += hwd[i];
  }
  float hw0 = (float)(hwd[0] / z), hw1 = (float)(hwd[1] / z), hw2 = (float)(hwd[2] / z);

  init_state<<<32, 256, 0, stream>>>(bus, V0, v, th, m, pm, qm, counts);
  if (f16gb)
    build_T_cast<<<8192, 256, 0, stream>>>(G, Bm, Tb, Gh, Bh);
  else
    build_T<<<8192, 256, 0, stream>>>(G, Bm, Tb);
  edge_prep<<<BE_ / 256, 256, 0, stream>>>(ei, efeat, We, be, eb, srcf, dstf, counts);
  scan_kernel<<<1, 256, 0, stream>>>(counts, offs, cursor);
  scatter_kernel<<<BE_ / 256, 256, 0, stream>>>(dstf, cursor, perm);
  edge_reorder<<<BE_ / 256, 256, 0, stream>>>(perm, srcf, eb, sp, ebp);
  prep_weights<<<(887912 + 255) / 256, 256, 0, stream>>>(
      Wq, bq, Wk, bk, Wv, bv, Wo, Wf1, Wf2, Wth, bth, Wvh, bvh, Wm, bm, Win,
      Wqkvt, bqkv, Wot, Wf1t, Wf2t, Wheads, bheads, Wint);

  for (int k = 0; k < 30; ++k) {
    if (f16gb)
      matvec_ns_f16<<<dim3(128, 4), 256, 0, stream>>>(Gh, Bh, v, th, P, Q, pm, qm,
                                                      m, nsT);
    else
      matvec_ns_f32<<<dim3(128, 4), 256, 0, stream>>>(G, Bm, v, th, P, Q, pm, qm,
                                                      m, nsT);
    {
      const _Float16* TbA = Tb;
      const _Float16* nsA = nsT;
      const _Float16* WiA = Wint;
      const float* binA = bin;
      void* kargs[] = {(void*)&TbA, (void*)&nsA, (void*)&H1, (void*)&H2,
                       (void*)&WiA, (void*)&binA, (void*)&hw0, (void*)&hw1,
                       (void*)&hw2, (void*)&x0, (void*)&xhA};
      hipLaunchCooperativeKernel(khop_chain, dim3(128, 4), dim3(256), kargs, 0,
                                 stream);
    }
    gemm_kernel<<<dim3(128, 12), 256, 0, stream>>>(xhA, Wqkvt, bqkv, nullptr, qkvh,
                                                   768, 256, 0);
    attn_kernel<<<2048, 256, 0, stream>>>(qkvh, offs, sp, ebp, xhB);
    oproj_ln1<<<512, 256, 0, stream>>>(xhB, Wot, bo, x0, g1, b1, x1, xhA);
    ffn_fused<<<256, 512, 0, stream>>>(xhA, Wf1t, bf1, Wf2t, bf2, x1, g2, b2,
                                       Wheads + k * 3072, bheads + k * 12,
                                       pm, qm, v, th, m);
  }
  out_kernel<<<32, 256, 0, stream>>>(v, th, out);
}

// Round 5
// 4791.463 us; speedup vs baseline: 1.6055x; 1.6055x over previous
//
#include <hip/hip_runtime.h>
#include <math.h>

typedef _Float16 f16x8 __attribute__((ext_vector_type(8)));
typedef _Float16 f16x4 __attribute__((ext_vector_type(4)));
typedef float f32x4 __attribute__((ext_vector_type(4)));

constexpr int B_ = 4, N_ = 2048, E_ = 16384;
constexpr int D_ = 10, DM_ = 256, NH_ = 8, FE_ = 9;
constexpr int BN_ = B_ * N_;   // 8192
constexpr int BE_ = B_ * E_;   // 65536

#define DEVI __device__ __forceinline__

DEVI _Float16 f2h(float f) { return (_Float16)f; }

// ---------------- setup kernels ----------------

__global__ void init_state(const int* __restrict__ bus, const float* __restrict__ V0,
                           float* v, float* th, float* m, float* pm, float* qm,
                           int* counts) {
  int t = blockIdx.x * blockDim.x + threadIdx.x;
  if (t >= BN_) return;
  int bt = bus[t];
  pm[t] = (bt == 1) ? 0.f : 1.f;
  qm[t] = (bt == 1 || bt == 2) ? 0.f : 1.f;
  v[t] = V0[2 * t];
  th[t] = V0[2 * t + 1];
  for (int d = 0; d < D_; ++d) m[(size_t)t * D_ + d] = 0.f;
  counts[t] = 0;
}

// one pass over G,Bm: write T (row-normalized adjacency) + fp16 copies of G,Bm
__global__ __launch_bounds__(256) void build_T_cast(const float* __restrict__ G,
    const float* __restrict__ Bm, _Float16* __restrict__ Tb,
    _Float16* __restrict__ Gh, _Float16* __restrict__ Bh) {
  int row = blockIdx.x;
  int i = row & (N_ - 1);
  const float* Gr = G + (size_t)row * N_;
  const float* Br = Bm + (size_t)row * N_;
  float a[8];
  float s = 0.f;
#pragma unroll
  for (int u = 0; u < 8; ++u) {
    int j = threadIdx.x + u * 256;
    float g = Gr[j], b = Br[j];
    if (Gh) { Gh[(size_t)row * N_ + j] = f2h(g); Bh[(size_t)row * N_ + j] = f2h(b); }
    float av = sqrtf(g * g + b * b);
    if (j == i) av = 0.f;
    a[u] = av;
    s += av;
  }
  __shared__ float red[4];
  for (int off = 32; off; off >>= 1) s += __shfl_down(s, off);
  int lane = threadIdx.x & 63, wave = threadIdx.x >> 6;
  if (lane == 0) red[wave] = s;
  __syncthreads();
  float tot = red[0] + red[1] + red[2] + red[3];
  float inv = 1.f / fmaxf(tot, 1e-12f);
#pragma unroll
  for (int u = 0; u < 8; ++u) {
    int j = threadIdx.x + u * 256;
    Tb[(size_t)row * N_ + j] = f2h(a[u] * inv);
  }
}

// 64x64 tiled fp16 transpose (per batch)
__global__ __launch_bounds__(256) void transpose16(const _Float16* __restrict__ in,
                                                   _Float16* __restrict__ out) {
  __shared__ float tile[64][65];
  int b = blockIdx.z;
  const _Float16* A = in + (size_t)b * N_ * N_;
  _Float16* O = out + (size_t)b * N_ * N_;
  int r0 = blockIdx.y * 64, c0 = blockIdx.x * 64;
  int tc = threadIdx.x & 63, tg = threadIdx.x >> 6;
#pragma unroll
  for (int i = 0; i < 16; ++i) {
    int r = tg * 16 + i;
    tile[r][tc] = (float)A[(size_t)(r0 + r) * N_ + c0 + tc];
  }
  __syncthreads();
#pragma unroll
  for (int i = 0; i < 16; ++i) {
    int r = tg * 16 + i;
    O[(size_t)(c0 + r) * N_ + r0 + tc] = f2h(tile[tc][r]);
  }
}

// batched C = A @ Bt^T (64x64 tile / block); optional epilogue:
// out = w3*C + w1*M1 + w2*M2  (all fp16 NxN matrices, per batch)
__global__ __launch_bounds__(256) void gemm_bat(const _Float16* __restrict__ A,
    const _Float16* __restrict__ Bt, _Float16* __restrict__ Cout,
    const _Float16* __restrict__ M1, const _Float16* __restrict__ M2,
    float w1, float w2, float w3) {
  int b = blockIdx.z;
  const _Float16* Ab = A + (size_t)b * N_ * N_;
  const _Float16* Bb = Bt + (size_t)b * N_ * N_;
  int wave = threadIdx.x >> 6, lane = threadIdx.x & 63;
  int wy = wave >> 1, wx = wave & 1;
  int m0 = blockIdx.x * 64 + wy * 32;
  int n0 = blockIdx.y * 64 + wx * 32;
  int lm = lane & 15, lq = lane >> 4;
  f32x4 acc[2][2] = {};
  const _Float16* A0 = Ab + (size_t)(m0 + lm) * N_ + lq * 8;
  const _Float16* A1 = A0 + (size_t)16 * N_;
  const _Float16* B0 = Bb + (size_t)(n0 + lm) * N_ + lq * 8;
  const _Float16* B1 = B0 + (size_t)16 * N_;
  for (int k = 0; k < N_; k += 32) {
    f16x8 a0 = *(const f16x8*)(A0 + k);
    f16x8 a1 = *(const f16x8*)(A1 + k);
    f16x8 b0 = *(const f16x8*)(B0 + k);
    f16x8 b1 = *(const f16x8*)(B1 + k);
    acc[0][0] = __builtin_amdgcn_mfma_f32_16x16x32_f16(a0, b0, acc[0][0], 0, 0, 0);
    acc[0][1] = __builtin_amdgcn_mfma_f32_16x16x32_f16(a0, b1, acc[0][1], 0, 0, 0);
    acc[1][0] = __builtin_amdgcn_mfma_f32_16x16x32_f16(a1, b0, acc[1][0], 0, 0, 0);
    acc[1][1] = __builtin_amdgcn_mfma_f32_16x16x32_f16(a1, b1, acc[1][1], 0, 0, 0);
  }
  _Float16* Cb = Cout + (size_t)b * N_ * N_;
#pragma unroll
  for (int tm = 0; tm < 2; ++tm)
#pragma unroll
    for (int tn = 0; tn < 2; ++tn) {
      int col = n0 + tn * 16 + lm;
#pragma unroll
      for (int r = 0; r < 4; ++r) {
        int row = m0 + tm * 16 + lq * 4 + r;
        size_t o = (size_t)b * N_ * N_ + (size_t)row * N_ + col;
        float val = acc[tm][tn][r];
        if (M1) val = w3 * val + w1 * (float)M1[o] + w2 * (float)M2[o];
        Cb[(size_t)row * N_ + col] = f2h(val);
      }
    }
}

__global__ void edge_prep(const int* __restrict__ ei, const float* __restrict__ efeat,
    const float* __restrict__ We, const float* __restrict__ be,
    float* __restrict__ eb, int* __restrict__ srcf, int* __restrict__ dstf,
    int* __restrict__ counts) {
  int t = blockIdx.x * blockDim.x + threadIdx.x;
  if (t >= BE_) return;
  int b = t / E_, e = t - b * E_;
  int src = ei[(size_t)b * 2 * E_ + e];
  int dst = ei[(size_t)b * 2 * E_ + E_ + e];
  srcf[t] = src + b * N_;
  int df = dst + b * N_;
  dstf[t] = df;
  atomicAdd(&counts[df], 1);
  float fv[FE_];
#pragma unroll
  for (int f = 0; f < FE_; ++f) fv[f] = efeat[(size_t)t * FE_ + f];
#pragma unroll
  for (int h = 0; h < NH_; ++h) {
    float s = be[h];
#pragma unroll
    for (int f = 0; f < FE_; ++f) s += fv[f] * We[f * NH_ + h];
    eb[(size_t)t * NH_ + h] = s;
  }
}

__global__ void scan_kernel(const int* __restrict__ counts, int* __restrict__ offs,
                            int* __restrict__ cursor) {
  __shared__ int part[256];
  int t = threadIdx.x;
  int base = t * 32;
  int loc[32];
  int s = 0;
#pragma unroll
  for (int i = 0; i < 32; ++i) { loc[i] = counts[base + i]; s += loc[i]; }
  part[t] = s;
  __syncthreads();
  for (int off = 1; off < 256; off <<= 1) {
    int vv = (t >= off) ? part[t - off] : 0;
    __syncthreads();
    part[t] += vv;
    __syncthreads();
  }
  int run = part[t] - s;
#pragma unroll
  for (int i = 0; i < 32; ++i) {
    offs[base + i] = run;
    cursor[base + i] = run;
    run += loc[i];
  }
  if (t == 255) offs[BN_] = run;
}

__global__ void scatter_kernel(const int* __restrict__ dstf, int* cursor,
                               int* __restrict__ perm) {
  int t = blockIdx.x * blockDim.x + threadIdx.x;
  if (t >= BE_) return;
  int d = dstf[t];
  int pos = atomicAdd(&cursor[d], 1);
  perm[pos] = t;
}

__global__ void edge_reorder(const int* __restrict__ perm, const int* __restrict__ srcf,
                             const float* __restrict__ eb, int* __restrict__ sp,
                             float* __restrict__ ebp) {
  int j = blockIdx.x * 256 + threadIdx.x;
  if (j >= BE_) return;
  int e = perm[j];
  sp[j] = srcf[e];
#pragma unroll
  for (int h = 0; h < NH_; ++h) ebp[(size_t)j * 8 + h] = eb[(size_t)e * 8 + h];
}

__global__ void prep_weights(const float* Wq, const float* bq, const float* Wk,
    const float* bk, const float* Wv, const float* bvv, const float* Wo,
    const float* Wf1, const float* Wf2, const float* Wth, const float* bth,
    const float* Wvh, const float* bvh, const float* Wm, const float* bm,
    const float* Win,
    _Float16* Wqkvt, float* bqkv, _Float16* Wot,
    _Float16* Wf1t, _Float16* Wf2t, float* Wheads, float* bheads,
    _Float16* Wint) {
  int i = blockIdx.x * blockDim.x + threadIdx.x;
  if (i < 768 * 256) {
    int n = i >> 8, kk = i & 255;
    float val = n < 256 ? Wq[kk * 256 + n]
              : n < 512 ? Wk[kk * 256 + (n - 256)] : Wv[kk * 256 + (n - 512)];
    Wqkvt[n * 256 + kk] = f2h(val);
    return;
  }
  i -= 768 * 256;
  if (i < 256 * 256) {
    int n = i >> 8, kk = i & 255;
    Wot[n * 256 + kk] = f2h(Wo[kk * 256 + n]);
    return;
  }
  i -= 256 * 256;
  if (i < 1024 * 256) {
    int n = i >> 8, kk = i & 255;
    Wf1t[n * 256 + kk] = f2h(Wf1[kk * 1024 + n]);
    return;
  }
  i -= 1024 * 256;
  if (i < 256 * 1024) {
    int n = i >> 10, kk = i & 1023;
    Wf2t[n * 1024 + kk] = f2h(Wf2[kk * 256 + n]);
    return;
  }
  i -= 256 * 1024;
  if (i < 30 * 3072) {
    int k = i / 3072, j = i - k * 3072;
    int row = j / 12, o = j - row * 12;
    float val = o == 0 ? Wth[k * 256 + row]
              : o == 1 ? Wvh[k * 256 + row] : Wm[k * 2560 + row * 10 + (o - 2)];
    Wheads[k * 3072 + j] = val;
    return;
  }
  i -= 30 * 3072;
  if (i < 360) {
    int k = i / 12, o = i - k * 12;
    bheads[i] = o == 0 ? bth[k] : o == 1 ? bvh[k] : bm[k * 10 + (o - 2)];
    return;
  }
  i -= 360;
  if (i < 768) {
    bqkv[i] = i < 256 ? bq[i] : i < 512 ? bk[i - 256] : bvv[i - 512];
    return;
  }
  i -= 768;
  if (i < 256 * 32) {
    int n = i >> 5, kk = i & 31;
    Wint[n * 32 + kk] = (kk < 28) ? f2h(Win[kk * 256 + n]) : (_Float16)0.f;
  }
}

// ---------------- per-step kernels ----------------

DEVI void ns_epilogue(int b, int row, float sre, float sim, int lane,
                      const float2* sef, const float* v, const float* th,
                      const float* P, const float* Q, const float* pm,
                      const float* qm, const float* m, _Float16* nsT) {
  for (int off = 1; off < 64; off <<= 1) {
    sre += __shfl_xor(sre, off);
    sim += __shfl_xor(sim, off);
  }
  if (lane < 16) {
    int node = b * N_ + row;
    float val;
    if (lane == 0) val = v[node];
    else if (lane == 1) val = th[node];
    else if (lane == 2) {
      float2 ef = sef[row];
      val = (P[node] - (ef.x * sre + ef.y * sim)) * pm[node];
    } else if (lane == 3) {
      float2 ef = sef[row];
      val = (Q[node] - (ef.y * sre - ef.x * sim)) * qm[node];
    } else if (lane < 14) val = m[(size_t)node * 10 + (lane - 4)];
    else val = 0.f;
    nsT[(size_t)b * 16 * N_ + (size_t)lane * N_ + row] = f2h(val);
  }
}

__global__ __launch_bounds__(256) void matvec_ns_f16(const _Float16* __restrict__ Gh,
    const _Float16* __restrict__ Bh, const float* __restrict__ v,
    const float* __restrict__ th, const float* __restrict__ P,
    const float* __restrict__ Q, const float* __restrict__ pm,
    const float* __restrict__ qm, const float* __restrict__ m,
    _Float16* __restrict__ nsT) {
  int b = blockIdx.y;
  __shared__ float2 sef[N_];
  for (int i = threadIdx.x; i < N_; i += 256) {
    float vv = v[b * N_ + i], tt = th[b * N_ + i];
    float sn, cs;
    __sincosf(tt, &sn, &cs);
    sef[i] = make_float2(vv * cs, vv * sn);
  }
  __syncthreads();
  int wave = threadIdx.x >> 6, lane = threadIdx.x & 63;
  for (int rr = 0; rr < 4; ++rr) {
    int row = blockIdx.x * 16 + wave * 4 + rr;
    const _Float16* Gr = Gh + ((size_t)b * N_ + row) * N_;
    const _Float16* Br = Bh + ((size_t)b * N_ + row) * N_;
    float sre = 0.f, sim = 0.f;
#pragma unroll
    for (int jj = 0; jj < 4; ++jj) {
      int j = lane * 8 + jj * 512;
      f16x8 g8 = *(const f16x8*)(Gr + j);
      f16x8 b8 = *(const f16x8*)(Br + j);
#pragma unroll
      for (int u = 0; u < 8; ++u) {
        float g = (float)g8[u], bb = (float)b8[u];
        float2 ef = sef[j + u];
        sre += g * ef.x - bb * ef.y;
        sim += g * ef.y + bb * ef.x;
      }
    }
    ns_epilogue(b, row, sre, sim, lane, sef, v, th, P, Q, pm, qm, m, nsT);
  }
}

__global__ __launch_bounds__(256) void matvec_ns_f32(const float* __restrict__ G,
    const float* __restrict__ Bm, const float* __restrict__ v,
    const float* __restrict__ th, const float* __restrict__ P,
    const float* __restrict__ Q, const float* __restrict__ pm,
    const float* __restrict__ qm, const float* __restrict__ m,
    _Float16* __restrict__ nsT) {
  int b = blockIdx.y;
  __shared__ float2 sef[N_];
  for (int i = threadIdx.x; i < N_; i += 256) {
    float vv = v[b * N_ + i], tt = th[b * N_ + i];
    float sn, cs;
    __sincosf(tt, &sn, &cs);
    sef[i] = make_float2(vv * cs, vv * sn);
  }
  __syncthreads();
  int wave = threadIdx.x >> 6, lane = threadIdx.x & 63;
  for (int rr = 0; rr < 4; ++rr) {
    int row = blockIdx.x * 16 + wave * 4 + rr;
    const float* Gr = G + ((size_t)b * N_ + row) * N_;
    const float* Br = Bm + ((size_t)b * N_ + row) * N_;
    float sre = 0.f, sim = 0.f;
#pragma unroll
    for (int jj = 0; jj < 8; ++jj) {
      int j = lane * 4 + jj * 256;
      float4 g4 = *(const float4*)(Gr + j);
      float4 b4 = *(const float4*)(Br + j);
      float2 e0 = sef[j], e1 = sef[j + 1], e2 = sef[j + 2], e3 = sef[j + 3];
      sre += g4.x * e0.x - b4.x * e0.y + g4.y * e1.x - b4.y * e1.y
           + g4.z * e2.x - b4.z * e2.y + g4.w * e3.x - b4.w * e3.y;
      sim += g4.x * e0.y + b4.x * e0.x + g4.y * e1.y + b4.y * e1.x
           + g4.z * e2.y + b4.z * e2.x + g4.w * e3.y + b4.w * e3.x;
    }
    ns_epilogue(b, row, sre, sim, lane, sef, v, th, P, Q, pm, qm, m, nsT);
  }
}

// one 16-node x 16-channel tile of (Tm @ Hin)^T
DEVI float khop_tile(const _Float16* __restrict__ Tm, const _Float16* __restrict__ Hin,
                     int b, int m0, int wave, int lm, int lq, int tid,
                     float (*red)[16][17]) {
  f32x4 acc = {0.f, 0.f, 0.f, 0.f};
  const _Float16* Trow = Tm + ((size_t)b * N_ + m0 + lm) * N_ + wave * 512 + lq * 8;
  const _Float16* Hrow = Hin + ((size_t)b * 16 + lm) * N_ + wave * 512 + lq * 8;
#pragma unroll 4
  for (int k = 0; k < 512; k += 32) {
    f16x8 a = *(const f16x8*)(Trow + k);
    f16x8 hb = *(const f16x8*)(Hrow + k);
    acc = __builtin_amdgcn_mfma_f32_16x16x32_f16(a, hb, acc, 0, 0, 0);
  }
#pragma unroll
  for (int r = 0; r < 4; ++r) red[wave][lq * 4 + r][lm] = acc[r];
  __syncthreads();
  int c = tid >> 4, rr = tid & 15;
  float s = red[0][rr][c] + red[1][rr][c] + red[2][rr][c] + red[3][rr][c];
  __syncthreads();
  return s;
}

// FAST PATH: acc = Tmix @ ns in ONE pass, fused with input projection
__global__ __launch_bounds__(256) void khop_mix_input(
    const _Float16* __restrict__ Tmix, const _Float16* __restrict__ nsT,
    const _Float16* __restrict__ Wint, const float* __restrict__ bin,
    float* __restrict__ x0, _Float16* __restrict__ xh) {
  int b = blockIdx.y, m0 = blockIdx.x * 16;
  int tid = threadIdx.x;
  int wave = tid >> 6, lane = tid & 63;
  int lm = lane & 15, lq = lane >> 4;
  __shared__ float red[4][16][17];
  __shared__ _Float16 in28s[16][32];
  float s = khop_tile(Tmix, nsT, b, m0, wave, lm, lq, tid, red);
  int oc = tid >> 4, orr = tid & 15;
  size_t oidx = ((size_t)b * 16 + oc) * N_ + m0 + orr;
  if (oc < 14) {
    in28s[orr][oc] = nsT[oidx];
    in28s[orr][14 + oc] = f2h(s);
  } else if (oc == 14) {
    in28s[orr][28] = (_Float16)0.f;
    in28s[orr][29] = (_Float16)0.f;
  } else {
    in28s[orr][30] = (_Float16)0.f;
    in28s[orr][31] = (_Float16)0.f;
  }
  __syncthreads();
  f16x8 afrag = *(const f16x8*)(&in28s[lm][lq * 8]);
#pragma unroll
  for (int nt = 0; nt < 4; ++nt) {
    int n0 = wave * 64 + nt * 16;
    f16x8 bfrag = *(const f16x8*)(Wint + (size_t)(n0 + lm) * 32 + lq * 8);
    f32x4 c4 = {0.f, 0.f, 0.f, 0.f};
    c4 = __builtin_amdgcn_mfma_f32_16x16x32_f16(afrag, bfrag, c4, 0, 0, 0);
    float bv = bin[n0 + lm];
#pragma unroll
    for (int rg = 0; rg < 4; ++rg) {
      int rw = lq * 4 + rg;
      float val = c4[rg] + bv;
      size_t o = ((size_t)(b * N_ + m0 + rw)) * 256 + n0 + lm;
      x0[o] = val;
      xh[o] = f2h(val);
    }
  }
}

// FALLBACK PATH: single hop, acc (+)= w * hop
__global__ __launch_bounds__(256) void khop_kernel(const _Float16* __restrict__ Tb,
    const _Float16* __restrict__ HinT, _Float16* __restrict__ HoutT,
    float* __restrict__ accT, float w, int first) {
  int b = blockIdx.y, m0 = blockIdx.x * 16;
  int tid = threadIdx.x;
  int wave = tid >> 6, lane = tid & 63;
  int lm = lane & 15, lq = lane >> 4;
  __shared__ float red[4][16][17];
  float s = khop_tile(Tb, HinT, b, m0, wave, lm, lq, tid, red);
  int c = tid >> 4, r = tid & 15;
  size_t o = ((size_t)b * 16 + c) * N_ + m0 + r;
  if (HoutT) HoutT[o] = f2h(s);
  if (first) accT[o] = w * s; else accT[o] += w * s;
}

// FALLBACK: hop3 + input projection
__global__ __launch_bounds__(256) void khop3_input(const _Float16* __restrict__ Tb,
    const _Float16* __restrict__ HinT, const _Float16* __restrict__ nsT,
    const float* __restrict__ accT, const _Float16* __restrict__ Wint,
    const float* __restrict__ bin, float hw2,
    float* __restrict__ x0, _Float16* __restrict__ xh) {
  int b = blockIdx.y, m0 = blockIdx.x * 16;
  int tid = threadIdx.x;
  int wave = tid >> 6, lane = tid & 63;
  int lm = lane & 15, lq = lane >> 4;
  __shared__ float red[4][16][17];
  __shared__ _Float16 in28s[16][32];
  float s = khop_tile(Tb, HinT, b, m0, wave, lm, lq, tid, red);
  int oc = tid >> 4, orr = tid & 15;
  size_t oidx = ((size_t)b * 16 + oc) * N_ + m0 + orr;
  if (oc < 14) {
    float atot = accT[oidx] + hw2 * s;
    in28s[orr][oc] = nsT[oidx];
    in28s[orr][14 + oc] = f2h(atot);
  } else if (oc == 14) {
    in28s[orr][28] = (_Float16)0.f;
    in28s[orr][29] = (_Float16)0.f;
  } else {
    in28s[orr][30] = (_Float16)0.f;
    in28s[orr][31] = (_Float16)0.f;
  }
  __syncthreads();
  f16x8 afrag = *(const f16x8*)(&in28s[lm][lq * 8]);
#pragma unroll
  for (int nt = 0; nt < 4; ++nt) {
    int n0 = wave * 64 + nt * 16;
    f16x8 bfrag = *(const f16x8*)(Wint + (size_t)(n0 + lm) * 32 + lq * 8);
    f32x4 c4 = {0.f, 0.f, 0.f, 0.f};
    c4 = __builtin_amdgcn_mfma_f32_16x16x32_f16(afrag, bfrag, c4, 0, 0, 0);
    float bv = bin[n0 + lm];
#pragma unroll
    for (int rg = 0; rg < 4; ++rg) {
      int rw = lq * 4 + rg;
      float val = c4[rg] + bv;
      size_t o = ((size_t)(b * N_ + m0 + rw)) * 256 + n0 + lm;
      x0[o] = val;
      xh[o] = f2h(val);
    }
  }
}

// generic C(M,N) = A @ Wt^T + bias (used for QKV)
__global__ __launch_bounds__(256) void gemm_kernel(const _Float16* __restrict__ A,
    const _Float16* __restrict__ Wt, const float* __restrict__ bias,
    float* __restrict__ Cf, _Float16* __restrict__ Ch,
    int N, int K, int relu) {
  int wave = threadIdx.x >> 6, lane = threadIdx.x & 63;
  int wy = wave >> 1, wx = wave & 1;
  int m0 = blockIdx.x * 64 + wy * 32;
  int n0 = blockIdx.y * 64 + wx * 32;
  int lm = lane & 15, lq = lane >> 4;
  f32x4 acc[2][2] = {};
  const _Float16* A0 = A + (size_t)(m0 + lm) * K + lq * 8;
  const _Float16* A1 = A0 + (size_t)16 * K;
  const _Float16* B0 = Wt + (size_t)(n0 + lm) * K + lq * 8;
  const _Float16* B1 = B0 + (size_t)16 * K;
  for (int k = 0; k < K; k += 32) {
    f16x8 a0 = *(const f16x8*)(A0 + k);
    f16x8 a1 = *(const f16x8*)(A1 + k);
    f16x8 b0 = *(const f16x8*)(B0 + k);
    f16x8 b1 = *(const f16x8*)(B1 + k);
    acc[0][0] = __builtin_amdgcn_mfma_f32_16x16x32_f16(a0, b0, acc[0][0], 0, 0, 0);
    acc[0][1] = __builtin_amdgcn_mfma_f32_16x16x32_f16(a0, b1, acc[0][1], 0, 0, 0);
    acc[1][0] = __builtin_amdgcn_mfma_f32_16x16x32_f16(a1, b0, acc[1][0], 0, 0, 0);
    acc[1][1] = __builtin_amdgcn_mfma_f32_16x16x32_f16(a1, b1, acc[1][1], 0, 0, 0);
  }
#pragma unroll
  for (int tm = 0; tm < 2; ++tm)
#pragma unroll
    for (int tn = 0; tn < 2; ++tn) {
      int col = n0 + tn * 16 + lm;
      float bvv = bias ? bias[col] : 0.f;
#pragma unroll
      for (int r = 0; r < 4; ++r) {
        int row = m0 + tm * 16 + lq * 4 + r;
        float val = acc[tm][tn][r] + bvv;
        if (relu) val = fmaxf(val, 0.f);
        size_t o = (size_t)row * N + col;
        if (Cf) Cf[o] = val;
        if (Ch) Ch[o] = f2h(val);
      }
    }
}

// one wave per node; software-pipelined edge gather
__global__ __launch_bounds__(256) void attn_kernel(const _Float16* __restrict__ qkv,
    const int* __restrict__ offs, const int* __restrict__ sp,
    const float* __restrict__ ebp, _Float16* __restrict__ aggh) {
  int node = blockIdx.x * 4 + (threadIdx.x >> 6);
  int lane = threadIdx.x & 63;
  int h = lane >> 3;
  f16x4 qh = *(const f16x4*)(qkv + (size_t)node * 768 + lane * 4);
  float4 q4 = {(float)qh[0], (float)qh[1], (float)qh[2], (float)qh[3]};
  int beg = offs[node], end = offs[node + 1];
  float mx = -3.0e38f, den = 0.f;
  float4 acc = {0.f, 0.f, 0.f, 0.f};
  f16x4 kh_n = {}, vh_n = {};
  float eb_n = 0.f;
  if (beg < end) {
    int s = sp[beg];
    const _Float16* base = qkv + (size_t)s * 768 + lane * 4;
    kh_n = *(const f16x4*)(base + 256);
    vh_n = *(const f16x4*)(base + 512);
    eb_n = ebp[(size_t)beg * 8 + h];
  }
  for (int j = beg; j < end; ++j) {
    f16x4 kh = kh_n, vh = vh_n;
    float ebv = eb_n;
    if (j + 1 < end) {
      int s2 = sp[j + 1];
      const _Float16* b2 = qkv + (size_t)s2 * 768 + lane * 4;
      kh_n = *(const f16x4*)(b2 + 256);
      vh_n = *(const f16x4*)(b2 + 512);
      eb_n = ebp[(size_t)(j + 1) * 8 + h];
    }
    float p = q4.x * (float)kh[0] + q4.y * (float)kh[1]
            + q4.z * (float)kh[2] + q4.w * (float)kh[3];
    p += __shfl_xor(p, 1);
    p += __shfl_xor(p, 2);
    p += __shfl_xor(p, 4);
    float score = p * 0.17677669529663687f + ebv;
    float nm = fmaxf(mx, score);
    float sc = __expf(mx - nm);
    float w = __expf(score - nm);
    den = den * sc + w;
    acc.x = acc.x * sc + w * (float)vh[0];
    acc.y = acc.y * sc + w * (float)vh[1];
    acc.z = acc.z * sc + w * (float)vh[2];
    acc.w = acc.w * sc + w * (float)vh[3];
    mx = nm;
  }
  float inv = den > 0.f ? 1.f / den : 0.f;
  f16x4 o;
  o[0] = f2h(acc.x * inv);
  o[1] = f2h(acc.y * inv);
  o[2] = f2h(acc.z * inv);
  o[3] = f2h(acc.w * inv);
  *(f16x4*)(aggh + (size_t)node * DM_ + lane * 4) = o;
}

// O-proj + residual + LN1 (M-tile 16, grid 512 blocks)
__global__ __launch_bounds__(256) void oproj_ln1(const _Float16* __restrict__ A,
    const _Float16* __restrict__ Wt, const float* __restrict__ bias,
    const float* __restrict__ res, const float* __restrict__ g,
    const float* __restrict__ bb, float* __restrict__ yF,
    _Float16* __restrict__ yH) {
  int m0 = blockIdx.x * 16;
  int wave = threadIdx.x >> 6, lane = threadIdx.x & 63;
  int lm = lane & 15, lq = lane >> 4;
  int n0 = wave * 64;
  f32x4 acc[4] = {};
  const _Float16* Ap = A + (size_t)(m0 + lm) * 256 + lq * 8;
  const _Float16* Bp = Wt + (size_t)(n0 + lm) * 256 + lq * 8;
  for (int k = 0; k < 256; k += 32) {
    f16x8 a0 = *(const f16x8*)(Ap + k);
#pragma unroll
    for (int nt = 0; nt < 4; ++nt) {
      f16x8 bf = *(const f16x8*)(Bp + nt * 16 * 256 + k);
      acc[nt] = __builtin_amdgcn_mfma_f32_16x16x32_f16(a0, bf, acc[nt], 0, 0, 0);
    }
  }
  float val[4][4];
  float rsum[4] = {}, rsq[4] = {};
#pragma unroll
  for (int nt = 0; nt < 4; ++nt) {
    int col = n0 + nt * 16 + lm;
    float bv = bias[col];
#pragma unroll
    for (int rg = 0; rg < 4; ++rg) {
      int row = m0 + lq * 4 + rg;
      float x = acc[nt][rg] + bv + res[(size_t)row * 256 + col];
      val[nt][rg] = x;
      rsum[rg] += x;
      rsq[rg] += x * x;
    }
  }
#pragma unroll
  for (int rg = 0; rg < 4; ++rg)
    for (int off = 1; off < 16; off <<= 1) {
      rsum[rg] += __shfl_xor(rsum[rg], off);
      rsq[rg] += __shfl_xor(rsq[rg], off);
    }
  __shared__ float redS[16][4], redQ[16][4];
  if (lm == 0) {
#pragma unroll
    for (int rg = 0; rg < 4; ++rg) {
      int r = lq * 4 + rg;
      redS[r][wave] = rsum[rg];
      redQ[r][wave] = rsq[rg];
    }
  }
  __syncthreads();
#pragma unroll
  for (int rg = 0; rg < 4; ++rg) {
    int r = lq * 4 + rg;
    float tS = redS[r][0] + redS[r][1] + redS[r][2] + redS[r][3];
    float tQ = redQ[r][0] + redQ[r][1] + redQ[r][2] + redQ[r][3];
    float mu = tS * (1.f / 256.f);
    float var = tQ * (1.f / 256.f) - mu * mu;
    float rs = rsqrtf(var + 1e-5f);
    int row = m0 + r;
#pragma unroll
    for (int nt = 0; nt < 4; ++nt) {
      int col = n0 + nt * 16 + lm;
      float y = g[col] * (val[nt][rg] - mu) * rs + bb[col];
      size_t o = (size_t)row * 256 + col;
      yF[o] = y;
      yH[o] = f2h(y);
    }
  }
}

// fused FFN: h=relu(x@Wf1+b) in LDS, y=h@Wf2+b, +res, LN2, heads, state update
__global__ __launch_bounds__(512) void ffn_fused(const _Float16* __restrict__ A,
    const _Float16* __restrict__ Wf1t, const float* __restrict__ bf1,
    const _Float16* __restrict__ Wf2t, const float* __restrict__ bf2,
    const float* __restrict__ res, const float* __restrict__ g,
    const float* __restrict__ bb, const float* __restrict__ Wh,
    const float* __restrict__ bh, const float* __restrict__ pm,
    const float* __restrict__ qm, float* __restrict__ v,
    float* __restrict__ th, float* __restrict__ m) {
  constexpr int HP = 1032;
  int m0 = blockIdx.x * 32;
  int tid = threadIdx.x;
  int wave = tid >> 6, lane = tid & 63;
  int lm = lane & 15, lq = lane >> 4;
  __shared__ _Float16 hs[32][HP];
  __shared__ float xs[32][261];
  __shared__ float whs[3072];
  __shared__ float part[32][193];
  __shared__ float redS[32][8], redQ[32][8];
  for (int i = tid; i < 3072; i += 512) whs[i] = Wh[i];
  {
    int n0 = wave * 128;
    f32x4 acc1[2][8] = {};
    const _Float16* Ap = A + (size_t)(m0 + lm) * 256 + lq * 8;
    const _Float16* Bp = Wf1t + (size_t)(n0 + lm) * 256 + lq * 8;
    for (int k = 0; k < 256; k += 32) {
      f16x8 a0 = *(const f16x8*)(Ap + k);
      f16x8 a1 = *(const f16x8*)(Ap + 16 * 256 + k);
#pragma unroll
      for (int nt = 0; nt < 8; ++nt) {
        f16x8 bf = *(const f16x8*)(Bp + nt * 16 * 256 + k);
        acc1[0][nt] = __builtin_amdgcn_mfma_f32_16x16x32_f16(a0, bf, acc1[0][nt], 0, 0, 0);
        acc1[1][nt] = __builtin_amdgcn_mfma_f32_16x16x32_f16(a1, bf, acc1[1][nt], 0, 0, 0);
      }
    }
#pragma unroll
    for (int mt = 0; mt < 2; ++mt)
#pragma unroll
      for (int nt = 0; nt < 8; ++nt) {
        int col = n0 + nt * 16 + lm;
        float bv = bf1[col];
#pragma unroll
        for (int rg = 0; rg < 4; ++rg) {
          int rloc = mt * 16 + lq * 4 + rg;
          hs[rloc][col] = f2h(fmaxf(acc1[mt][nt][rg] + bv, 0.f));
        }
      }
  }
  __syncthreads();
  float val[2][2][4];
  float rsum[2][4] = {}, rsq[2][4] = {};
  {
    int n0 = wave * 32;
    f32x4 acc2[2][2] = {};
    const _Float16* Bp = Wf2t + (size_t)(n0 + lm) * 1024 + lq * 8;
    for (int k = 0; k < 1024; k += 32) {
      f16x8 a0 = *(const f16x8*)(&hs[lm][k + lq * 8]);
      f16x8 a1 = *(const f16x8*)(&hs[16 + lm][k + lq * 8]);
      f16x8 b0 = *(const f16x8*)(Bp + k);
      f16x8 b1 = *(const f16x8*)(Bp + 16 * 1024 + k);
      acc2[0][0] = __builtin_amdgcn_mfma_f32_16x16x32_f16(a0, b0, acc2[0][0], 0, 0, 0);
      acc2[0][1] = __builtin_amdgcn_mfma_f32_16x16x32_f16(a0, b1, acc2[0][1], 0, 0, 0);
      acc2[1][0] = __builtin_amdgcn_mfma_f32_16x16x32_f16(a1, b0, acc2[1][0], 0, 0, 0);
      acc2[1][1] = __builtin_amdgcn_mfma_f32_16x16x32_f16(a1, b1, acc2[1][1], 0, 0, 0);
    }
#pragma unroll
    for (int mt = 0; mt < 2; ++mt)
#pragma unroll
      for (int nt = 0; nt < 2; ++nt) {
        int col = n0 + nt * 16 + lm;
        float bv = bf2[col];
#pragma unroll
        for (int rg = 0; rg < 4; ++rg) {
          int row = m0 + mt * 16 + lq * 4 + rg;
          float x = acc2[mt][nt][rg] + bv + res[(size_t)row * 256 + col];
          val[mt][nt][rg] = x;
          rsum[mt][rg] += x;
          rsq[mt][rg] += x * x;
        }
      }
  }
#pragma unroll
  for (int mt = 0; mt < 2; ++mt)
#pragma unroll
    for (int rg = 0; rg < 4; ++rg)
      for (int off = 1; off < 16; off <<= 1) {
        rsum[mt][rg] += __shfl_xor(rsum[mt][rg], off);
        rsq[mt][rg] += __shfl_xor(rsq[mt][rg], off);
      }
  if (lm == 0) {
#pragma unroll
    for (int mt = 0; mt < 2; ++mt)
#pragma unroll
      for (int rg = 0; rg < 4; ++rg) {
        int r = mt * 16 + lq * 4 + rg;
        redS[r][wave] = rsum[mt][rg];
        redQ[r][wave] = rsq[mt][rg];
      }
  }
  __syncthreads();
#pragma unroll
  for (int mt = 0; mt < 2; ++mt)
#pragma unroll
    for (int rg = 0; rg < 4; ++rg) {
      int r = mt * 16 + lq * 4 + rg;
      float tS = 0.f, tQ = 0.f;
#pragma unroll
      for (int w = 0; w < 8; ++w) { tS += redS[r][w]; tQ += redQ[r][w]; }
      float mu = tS * (1.f / 256.f);
      float var = tQ * (1.f / 256.f) - mu * mu;
      float rs = rsqrtf(var + 1e-5f);
#pragma unroll
      for (int nt = 0; nt < 2; ++nt) {
        int col = wave * 32 + nt * 16 + lm;
        xs[r][col] = g[col] * (val[mt][nt][rg] - mu) * rs + bb[col];
      }
    }
  __syncthreads();
  {
    int rw = tid & 31, grp = tid >> 5;
    float pa[12] = {};
    for (int c = 0; c < 16; ++c) {
      int col = grp * 16 + c;
      float xv = xs[rw][col];
#pragma unroll
      for (int o = 0; o < 12; ++o) pa[o] += xv * whs[col * 12 + o];
    }
#pragma unroll
    for (int o = 0; o < 12; ++o) part[rw][grp * 12 + o] = pa[o];
  }
  __syncthreads();
  if (tid < 32) {
    int node = m0 + tid;
    float tot[12];
#pragma unroll
    for (int o = 0; o < 12; ++o) {
      float s = bh[o];
#pragma unroll
      for (int grp = 0; grp < 16; ++grp) s += part[tid][grp * 12 + o];
      tot[o] = s;
    }
    th[node] += tot[0] * pm[node];
    v[node] += tot[1] * qm[node];
#pragma unroll
    for (int d = 0; d < 10; ++d) m[(size_t)node * 10 + d] = tot[2 + d];
  }
}

__global__ void out_kernel(const float* __restrict__ v, const float* __restrict__ th,
                           float* __restrict__ out) {
  int t = blockIdx.x * blockDim.x + threadIdx.x;
  if (t >= BN_) return;
  out[2 * t] = v[t];
  out[2 * t + 1] = th[t];
}

// ---------------- launcher ----------------

extern "C" void kernel_launch(void* const* d_in, const int* in_sizes, int n_in,
                              void* d_out, int out_size, void* d_ws, size_t ws_size,
                              hipStream_t stream) {
  const int* bus = (const int*)d_in[0];
  const int* ei = (const int*)d_in[1];
  const float* G = (const float*)d_in[2];
  const float* Bm = (const float*)d_in[3];
  const float* P = (const float*)d_in[4];
  const float* Q = (const float*)d_in[5];
  const float* V0 = (const float*)d_in[6];
  const float* efeat = (const float*)d_in[7];
  const float* Win = (const float*)d_in[8];
  const float* bin = (const float*)d_in[9];
  const float* Wq = (const float*)d_in[10];
  const float* bq = (const float*)d_in[11];
  const float* Wk = (const float*)d_in[12];
  const float* bk = (const float*)d_in[13];
  const float* Wv = (const float*)d_in[14];
  const float* bv = (const float*)d_in[15];
  const float* Wo = (const float*)d_in[16];
  const float* bo = (const float*)d_in[17];
  const float* We = (const float*)d_in[18];
  const float* be = (const float*)d_in[19];
  const float* g1 = (const float*)d_in[20];
  const float* b1 = (const float*)d_in[21];
  const float* g2 = (const float*)d_in[22];
  const float* b2 = (const float*)d_in[23];
  const float* Wf1 = (const float*)d_in[24];
  const float* bf1 = (const float*)d_in[25];
  const float* Wf2 = (const float*)d_in[26];
  const float* bf2 = (const float*)d_in[27];
  const float* Wth = (const float*)d_in[28];
  const float* bth = (const float*)d_in[29];
  const float* Wvh = (const float*)d_in[30];
  const float* bvh = (const float*)d_in[31];
  const float* Wm = (const float*)d_in[32];
  const float* bm = (const float*)d_in[33];
  float* out = (float*)d_out;

  char* p = (char*)d_ws;
  auto alloc = [&](size_t bytes) -> void* {
    void* r = (void*)p;
    p += (bytes + 255) & ~(size_t)255;
    return r;
  };
  _Float16* Tb = (_Float16*)alloc((size_t)BN_ * N_ * 2);     // 33.5 MB
  _Float16* nsT = (_Float16*)alloc((size_t)B_ * 16 * N_ * 2);
  _Float16* H1 = (_Float16*)alloc((size_t)B_ * 16 * N_ * 2);
  _Float16* H2 = (_Float16*)alloc((size_t)B_ * 16 * N_ * 2);
  float* accT = (float*)alloc((size_t)B_ * 16 * N_ * 4);
  _Float16* qkvh = (_Float16*)alloc((size_t)BN_ * 768 * 2);
  float* x0 = (float*)alloc((size_t)BN_ * 256 * 4);
  float* x1 = (float*)alloc((size_t)BN_ * 256 * 4);
  _Float16* xhA = (_Float16*)alloc((size_t)BN_ * 256 * 2);
  _Float16* xhB = (_Float16*)alloc((size_t)BN_ * 256 * 2);
  float* eb = (float*)alloc((size_t)BE_ * 8 * 4);
  float* ebp = (float*)alloc((size_t)BE_ * 8 * 4);
  int* srcf = (int*)alloc((size_t)BE_ * 4);
  int* dstf = (int*)alloc((size_t)BE_ * 4);
  int* sp = (int*)alloc((size_t)BE_ * 4);
  int* counts = (int*)alloc((size_t)BN_ * 4);
  int* offs = (int*)alloc((size_t)(BN_ + 1) * 4);
  int* cursor = (int*)alloc((size_t)BN_ * 4);
  int* perm = (int*)alloc((size_t)BE_ * 4);
  _Float16* Wqkvt = (_Float16*)alloc(768 * 256 * 2);
  _Float16* Wot = (_Float16*)alloc(256 * 256 * 2);
  _Float16* Wf1t = (_Float16*)alloc(1024 * 256 * 2);
  _Float16* Wf2t = (_Float16*)alloc(256 * 1024 * 2);
  _Float16* Wint = (_Float16*)alloc(256 * 32 * 2);
  float* Wheads = (float*)alloc(30 * 3072 * 4);
  float* bheads = (float*)alloc(30 * 12 * 4);
  float* bqkv = (float*)alloc(768 * 4);
  float* v = (float*)alloc((size_t)BN_ * 4);
  float* th = (float*)alloc((size_t)BN_ * 4);
  float* pm = (float*)alloc((size_t)BN_ * 4);
  float* qm = (float*)alloc((size_t)BN_ * 4);
  float* m = (float*)alloc((size_t)BN_ * 10 * 4);

  size_t nn2 = (size_t)B_ * N_ * N_ * 2;  // 33.5 MB
  size_t used = (size_t)(p - (char*)d_ws);
  // priority 1: Tmix precompute buffers (3 x 33.5 MB)
  bool tmix_ok = (used + 3 * (nn2 + 256) <= ws_size);
  _Float16 *Tt = nullptr, *T2 = nullptr, *Tmix = nullptr;
  if (tmix_ok) {
    Tt = (_Float16*)alloc(nn2);
    T2 = (_Float16*)alloc(nn2);
    Tmix = (_Float16*)alloc(nn2);
  }
  // priority 2: fp16 G/Bm (2 x 33.5 MB)
  used = (size_t)(p - (char*)d_ws);
  bool f16gb = (used + 2 * (nn2 + 256) <= ws_size);
  _Float16 *Gh = nullptr, *Bh = nullptr;
  if (f16gb) {
    Gh = (_Float16*)alloc(nn2);
    Bh = (_Float16*)alloc(nn2);
  }

  double hwd[3], z = 0.0;
  for (int i = 0; i < 3; ++i) {
    hwd[i] = exp(-((double)(i + 1) * (i + 1)) / (2.0 * 1.5 * 1.5));
    z += hwd[i];
  }
  float hw0 = (float)(hwd[0] / z), hw1 = (float)(hwd[1] / z), hw2 = (float)(hwd[2] / z);

  init_state<<<32, 256, 0, stream>>>(bus, V0, v, th, m, pm, qm, counts);
  build_T_cast<<<8192, 256, 0, stream>>>(G, Bm, Tb, Gh, Bh);
  if (tmix_ok) {
    transpose16<<<dim3(32, 32, 4), 256, 0, stream>>>(Tb, Tt);
    // T2 = T @ T
    gemm_bat<<<dim3(32, 32, 4), 256, 0, stream>>>(Tb, Tt, T2,
        (const _Float16*)nullptr, (const _Float16*)nullptr, 0.f, 0.f, 0.f);
    // Tmix = hw0*T + hw1*T2 + hw2*(T2 @ T)
    gemm_bat<<<dim3(32, 32, 4), 256, 0, stream>>>(T2, Tt, Tmix, Tb, T2,
                                                  hw0, hw1, hw2);
  }
  edge_prep<<<BE_ / 256, 256, 0, stream>>>(ei, efeat, We, be, eb, srcf, dstf, counts);
  scan_kernel<<<1, 256, 0, stream>>>(counts, offs, cursor);
  scatter_kernel<<<BE_ / 256, 256, 0, stream>>>(dstf, cursor, perm);
  edge_reorder<<<BE_ / 256, 256, 0, stream>>>(perm, srcf, eb, sp, ebp);
  prep_weights<<<(887912 + 255) / 256, 256, 0, stream>>>(
      Wq, bq, Wk, bk, Wv, bv, Wo, Wf1, Wf2, Wth, bth, Wvh, bvh, Wm, bm, Win,
      Wqkvt, bqkv, Wot, Wf1t, Wf2t, Wheads, bheads, Wint);

  for (int k = 0; k < 30; ++k) {
    if (f16gb)
      matvec_ns_f16<<<dim3(128, 4), 256, 0, stream>>>(Gh, Bh, v, th, P, Q, pm, qm,
                                                      m, nsT);
    else
      matvec_ns_f32<<<dim3(128, 4), 256, 0, stream>>>(G, Bm, v, th, P, Q, pm, qm,
                                                      m, nsT);
    if (tmix_ok) {
      khop_mix_input<<<dim3(128, 4), 256, 0, stream>>>(Tmix, nsT, Wint, bin,
                                                       x0, xhA);
    } else {
      khop_kernel<<<dim3(128, 4), 256, 0, stream>>>(Tb, nsT, H1, accT, hw0, 1);
      khop_kernel<<<dim3(128, 4), 256, 0, stream>>>(Tb, H1, H2, accT, hw1, 0);
      khop3_input<<<dim3(128, 4), 256, 0, stream>>>(Tb, H2, nsT, accT, Wint, bin,
                                                    hw2, x0, xhA);
    }
    gemm_kernel<<<dim3(128, 12), 256, 0, stream>>>(xhA, Wqkvt, bqkv, nullptr, qkvh,
                                                   768, 256, 0);
    attn_kernel<<<2048, 256, 0, stream>>>(qkvh, offs, sp, ebp, xhB);
    oproj_ln1<<<512, 256, 0, stream>>>(xhB, Wot, bo, x0, g1, b1, x1, xhA);
    ffn_fused<<<256, 512, 0, stream>>>(xhA, Wf1t, bf1, Wf2t, bf2, x1, g2, b2,
                                       Wheads + k * 3072, bheads + k * 12,
                                       pm, qm, v, th, m);
  }
  out_kernel<<<32, 256, 0, stream>>>(v, th, out);
}

// Round 6
// 4617.639 us; speedup vs baseline: 1.6660x; 1.0376x over previous
//
#include <hip/hip_runtime.h>
#include <math.h>

typedef _Float16 f16x8 __attribute__((ext_vector_type(8)));
typedef _Float16 f16x4 __attribute__((ext_vector_type(4)));
typedef float f32x4 __attribute__((ext_vector_type(4)));

constexpr int B_ = 4, N_ = 2048, E_ = 16384;
constexpr int D_ = 10, DM_ = 256, NH_ = 8, FE_ = 9;
constexpr int BN_ = B_ * N_;   // 8192
constexpr int BE_ = B_ * E_;   // 65536

#define DEVI __device__ __forceinline__

DEVI _Float16 f2h(float f) { return (_Float16)f; }

// ---------------- setup kernels ----------------

__global__ void init_state(const int* __restrict__ bus, const float* __restrict__ V0,
                           float* v, float* th, float* m, float* pm, float* qm,
                           int* counts) {
  int t = blockIdx.x * blockDim.x + threadIdx.x;
  if (t >= BN_) return;
  int bt = bus[t];
  pm[t] = (bt == 1) ? 0.f : 1.f;
  qm[t] = (bt == 1 || bt == 2) ? 0.f : 1.f;
  v[t] = V0[2 * t];
  th[t] = V0[2 * t + 1];
  for (int d = 0; d < D_; ++d) m[(size_t)t * D_ + d] = 0.f;
  counts[t] = 0;
}

// one pass over G,Bm: write T (row-normalized adjacency) + fp16 copies of G,Bm
__global__ __launch_bounds__(256) void build_T_cast(const float* __restrict__ G,
    const float* __restrict__ Bm, _Float16* __restrict__ Tb,
    _Float16* __restrict__ Gh, _Float16* __restrict__ Bh) {
  int row = blockIdx.x;
  int i = row & (N_ - 1);
  const float* Gr = G + (size_t)row * N_;
  const float* Br = Bm + (size_t)row * N_;
  float a[8];
  float s = 0.f;
#pragma unroll
  for (int u = 0; u < 8; ++u) {
    int j = threadIdx.x + u * 256;
    float g = Gr[j], b = Br[j];
    if (Gh) { Gh[(size_t)row * N_ + j] = f2h(g); Bh[(size_t)row * N_ + j] = f2h(b); }
    float av = sqrtf(g * g + b * b);
    if (j == i) av = 0.f;
    a[u] = av;
    s += av;
  }
  __shared__ float red[4];
  for (int off = 32; off; off >>= 1) s += __shfl_down(s, off);
  int lane = threadIdx.x & 63, wave = threadIdx.x >> 6;
  if (lane == 0) red[wave] = s;
  __syncthreads();
  float tot = red[0] + red[1] + red[2] + red[3];
  float inv = 1.f / fmaxf(tot, 1e-12f);
#pragma unroll
  for (int u = 0; u < 8; ++u) {
    int j = threadIdx.x + u * 256;
    Tb[(size_t)row * N_ + j] = f2h(a[u] * inv);
  }
}

// 64x64 tiled fp16 transpose (per batch)
__global__ __launch_bounds__(256) void transpose16(const _Float16* __restrict__ in,
                                                   _Float16* __restrict__ out) {
  __shared__ float tile[64][65];
  int b = blockIdx.z;
  const _Float16* A = in + (size_t)b * N_ * N_;
  _Float16* O = out + (size_t)b * N_ * N_;
  int r0 = blockIdx.y * 64, c0 = blockIdx.x * 64;
  int tc = threadIdx.x & 63, tg = threadIdx.x >> 6;
#pragma unroll
  for (int i = 0; i < 16; ++i) {
    int r = tg * 16 + i;
    tile[r][tc] = (float)A[(size_t)(r0 + r) * N_ + c0 + tc];
  }
  __syncthreads();
#pragma unroll
  for (int i = 0; i < 16; ++i) {
    int r = tg * 16 + i;
    O[(size_t)(c0 + r) * N_ + r0 + tc] = f2h(tile[tc][r]);
  }
}

// batched C = A @ Bt^T; 128x128 per block, 64x64 per wave (4x4 16x16x32 frags)
// optional epilogue: out = w3*C + w1*M1 + w2*M2
__global__ __launch_bounds__(256) void gemm_bat(const _Float16* __restrict__ A,
    const _Float16* __restrict__ Bt, _Float16* __restrict__ Cout,
    const _Float16* __restrict__ M1, const _Float16* __restrict__ M2,
    float w1, float w2, float w3) {
  int b = blockIdx.z;
  const _Float16* Ab = A + (size_t)b * N_ * N_;
  const _Float16* Bb = Bt + (size_t)b * N_ * N_;
  int wave = threadIdx.x >> 6, lane = threadIdx.x & 63;
  int wy = wave >> 1, wx = wave & 1;
  int m0 = blockIdx.x * 128 + wy * 64;
  int n0 = blockIdx.y * 128 + wx * 64;
  int lm = lane & 15, lq = lane >> 4;
  f32x4 acc[4][4] = {};
  const _Float16* Ap0 = Ab + (size_t)(m0 + lm) * N_ + lq * 8;
  const _Float16* Bp0 = Bb + (size_t)(n0 + lm) * N_ + lq * 8;
#pragma unroll 2
  for (int k = 0; k < N_; k += 32) {
    f16x8 af[4], bf[4];
#pragma unroll
    for (int i = 0; i < 4; ++i) {
      af[i] = *(const f16x8*)(Ap0 + (size_t)i * 16 * N_ + k);
      bf[i] = *(const f16x8*)(Bp0 + (size_t)i * 16 * N_ + k);
    }
#pragma unroll
    for (int mi = 0; mi < 4; ++mi)
#pragma unroll
      for (int ni = 0; ni < 4; ++ni)
        acc[mi][ni] = __builtin_amdgcn_mfma_f32_16x16x32_f16(af[mi], bf[ni],
                                                             acc[mi][ni], 0, 0, 0);
  }
  _Float16* Cb = Cout + (size_t)b * N_ * N_;
#pragma unroll
  for (int mi = 0; mi < 4; ++mi)
#pragma unroll
    for (int ni = 0; ni < 4; ++ni) {
      int col = n0 + ni * 16 + lm;
#pragma unroll
      for (int r = 0; r < 4; ++r) {
        int row = m0 + mi * 16 + lq * 4 + r;
        size_t o = (size_t)b * N_ * N_ + (size_t)row * N_ + col;
        float val = acc[mi][ni][r];
        if (M1) val = w3 * val + w1 * (float)M1[o] + w2 * (float)M2[o];
        Cb[(size_t)row * N_ + col] = f2h(val);
      }
    }
}

__global__ void edge_prep(const int* __restrict__ ei, const float* __restrict__ efeat,
    const float* __restrict__ We, const float* __restrict__ be,
    float* __restrict__ eb, int* __restrict__ srcf, int* __restrict__ dstf,
    int* __restrict__ counts) {
  int t = blockIdx.x * blockDim.x + threadIdx.x;
  if (t >= BE_) return;
  int b = t / E_, e = t - b * E_;
  int src = ei[(size_t)b * 2 * E_ + e];
  int dst = ei[(size_t)b * 2 * E_ + E_ + e];
  srcf[t] = src + b * N_;
  int df = dst + b * N_;
  dstf[t] = df;
  atomicAdd(&counts[df], 1);
  float fv[FE_];
#pragma unroll
  for (int f = 0; f < FE_; ++f) fv[f] = efeat[(size_t)t * FE_ + f];
#pragma unroll
  for (int h = 0; h < NH_; ++h) {
    float s = be[h];
#pragma unroll
    for (int f = 0; f < FE_; ++f) s += fv[f] * We[f * NH_ + h];
    eb[(size_t)t * NH_ + h] = s;
  }
}

__global__ void scan_kernel(const int* __restrict__ counts, int* __restrict__ offs,
                            int* __restrict__ cursor) {
  __shared__ int part[256];
  int t = threadIdx.x;
  int base = t * 32;
  int loc[32];
  int s = 0;
#pragma unroll
  for (int i = 0; i < 32; ++i) { loc[i] = counts[base + i]; s += loc[i]; }
  part[t] = s;
  __syncthreads();
  for (int off = 1; off < 256; off <<= 1) {
    int vv = (t >= off) ? part[t - off] : 0;
    __syncthreads();
    part[t] += vv;
    __syncthreads();
  }
  int run = part[t] - s;
#pragma unroll
  for (int i = 0; i < 32; ++i) {
    offs[base + i] = run;
    cursor[base + i] = run;
    run += loc[i];
  }
  if (t == 255) offs[BN_] = run;
}

__global__ void scatter_kernel(const int* __restrict__ dstf, int* cursor,
                               int* __restrict__ perm) {
  int t = blockIdx.x * blockDim.x + threadIdx.x;
  if (t >= BE_) return;
  int d = dstf[t];
  int pos = atomicAdd(&cursor[d], 1);
  perm[pos] = t;
}

__global__ void edge_reorder(const int* __restrict__ perm, const int* __restrict__ srcf,
                             const float* __restrict__ eb, int* __restrict__ sp,
                             float* __restrict__ ebp) {
  int j = blockIdx.x * 256 + threadIdx.x;
  if (j >= BE_) return;
  int e = perm[j];
  sp[j] = srcf[e];
#pragma unroll
  for (int h = 0; h < NH_; ++h) ebp[(size_t)j * 8 + h] = eb[(size_t)e * 8 + h];
}

__global__ void prep_weights(const float* Wq, const float* bq, const float* Wk,
    const float* bk, const float* Wv, const float* bvv, const float* Wo,
    const float* Wf1, const float* Wf2, const float* Wth, const float* bth,
    const float* Wvh, const float* bvh, const float* Wm, const float* bm,
    const float* Win,
    _Float16* Wqkvt, float* bqkv, _Float16* Wot,
    _Float16* Wf1t, _Float16* Wf2t, float* Wheads, float* bheads,
    _Float16* Wint) {
  int i = blockIdx.x * blockDim.x + threadIdx.x;
  if (i < 768 * 256) {
    int n = i >> 8, kk = i & 255;
    float val = n < 256 ? Wq[kk * 256 + n]
              : n < 512 ? Wk[kk * 256 + (n - 256)] : Wv[kk * 256 + (n - 512)];
    Wqkvt[n * 256 + kk] = f2h(val);
    return;
  }
  i -= 768 * 256;
  if (i < 256 * 256) {
    int n = i >> 8, kk = i & 255;
    Wot[n * 256 + kk] = f2h(Wo[kk * 256 + n]);
    return;
  }
  i -= 256 * 256;
  if (i < 1024 * 256) {
    int n = i >> 8, kk = i & 255;
    Wf1t[n * 256 + kk] = f2h(Wf1[kk * 1024 + n]);
    return;
  }
  i -= 1024 * 256;
  if (i < 256 * 1024) {
    int n = i >> 10, kk = i & 1023;
    Wf2t[n * 1024 + kk] = f2h(Wf2[kk * 256 + n]);
    return;
  }
  i -= 256 * 1024;
  if (i < 30 * 3072) {
    int k = i / 3072, j = i - k * 3072;
    int row = j / 12, o = j - row * 12;
    float val = o == 0 ? Wth[k * 256 + row]
              : o == 1 ? Wvh[k * 256 + row] : Wm[k * 2560 + row * 10 + (o - 2)];
    Wheads[k * 3072 + j] = val;
    return;
  }
  i -= 30 * 3072;
  if (i < 360) {
    int k = i / 12, o = i - k * 12;
    bheads[i] = o == 0 ? bth[k] : o == 1 ? bvh[k] : bm[k * 10 + (o - 2)];
    return;
  }
  i -= 360;
  if (i < 768) {
    bqkv[i] = i < 256 ? bq[i] : i < 512 ? bk[i - 256] : bvv[i - 512];
    return;
  }
  i -= 768;
  if (i < 256 * 32) {
    int n = i >> 5, kk = i & 31;
    Wint[n * 32 + kk] = (kk < 28) ? f2h(Win[kk * 256 + n]) : (_Float16)0.f;
  }
}

// ---------------- per-step kernels ----------------

DEVI void ns_epilogue(int b, int row, float sre, float sim, int lane,
                      const float2* sef, const float* v, const float* th,
                      const float* P, const float* Q, const float* pm,
                      const float* qm, const float* m, _Float16* nsT) {
  for (int off = 1; off < 64; off <<= 1) {
    sre += __shfl_xor(sre, off);
    sim += __shfl_xor(sim, off);
  }
  if (lane < 16) {
    int node = b * N_ + row;
    float val;
    if (lane == 0) val = v[node];
    else if (lane == 1) val = th[node];
    else if (lane == 2) {
      float2 ef = sef[row];
      val = (P[node] - (ef.x * sre + ef.y * sim)) * pm[node];
    } else if (lane == 3) {
      float2 ef = sef[row];
      val = (Q[node] - (ef.y * sre - ef.x * sim)) * qm[node];
    } else if (lane < 14) val = m[(size_t)node * 10 + (lane - 4)];
    else val = 0.f;
    nsT[(size_t)b * 16 * N_ + (size_t)lane * N_ + row] = f2h(val);
  }
}

__global__ __launch_bounds__(256) void matvec_ns_f16(const _Float16* __restrict__ Gh,
    const _Float16* __restrict__ Bh, const float* __restrict__ v,
    const float* __restrict__ th, const float* __restrict__ P,
    const float* __restrict__ Q, const float* __restrict__ pm,
    const float* __restrict__ qm, const float* __restrict__ m,
    _Float16* __restrict__ nsT) {
  int b = blockIdx.y;
  __shared__ float2 sef[N_];
  for (int i = threadIdx.x; i < N_; i += 256) {
    float vv = v[b * N_ + i], tt = th[b * N_ + i];
    float sn, cs;
    __sincosf(tt, &sn, &cs);
    sef[i] = make_float2(vv * cs, vv * sn);
  }
  __syncthreads();
  int wave = threadIdx.x >> 6, lane = threadIdx.x & 63;
  for (int rr = 0; rr < 4; ++rr) {
    int row = blockIdx.x * 16 + wave * 4 + rr;
    const _Float16* Gr = Gh + ((size_t)b * N_ + row) * N_;
    const _Float16* Br = Bh + ((size_t)b * N_ + row) * N_;
    float sre = 0.f, sim = 0.f;
#pragma unroll
    for (int jj = 0; jj < 4; ++jj) {
      int j = lane * 8 + jj * 512;
      f16x8 g8 = *(const f16x8*)(Gr + j);
      f16x8 b8 = *(const f16x8*)(Br + j);
#pragma unroll
      for (int u = 0; u < 8; ++u) {
        float g = (float)g8[u], bb = (float)b8[u];
        float2 ef = sef[j + u];
        sre += g * ef.x - bb * ef.y;
        sim += g * ef.y + bb * ef.x;
      }
    }
    ns_epilogue(b, row, sre, sim, lane, sef, v, th, P, Q, pm, qm, m, nsT);
  }
}

__global__ __launch_bounds__(256) void matvec_ns_f32(const float* __restrict__ G,
    const float* __restrict__ Bm, const float* __restrict__ v,
    const float* __restrict__ th, const float* __restrict__ P,
    const float* __restrict__ Q, const float* __restrict__ pm,
    const float* __restrict__ qm, const float* __restrict__ m,
    _Float16* __restrict__ nsT) {
  int b = blockIdx.y;
  __shared__ float2 sef[N_];
  for (int i = threadIdx.x; i < N_; i += 256) {
    float vv = v[b * N_ + i], tt = th[b * N_ + i];
    float sn, cs;
    __sincosf(tt, &sn, &cs);
    sef[i] = make_float2(vv * cs, vv * sn);
  }
  __syncthreads();
  int wave = threadIdx.x >> 6, lane = threadIdx.x & 63;
  for (int rr = 0; rr < 4; ++rr) {
    int row = blockIdx.x * 16 + wave * 4 + rr;
    const float* Gr = G + ((size_t)b * N_ + row) * N_;
    const float* Br = Bm + ((size_t)b * N_ + row) * N_;
    float sre = 0.f, sim = 0.f;
#pragma unroll
    for (int jj = 0; jj < 8; ++jj) {
      int j = lane * 4 + jj * 256;
      float4 g4 = *(const float4*)(Gr + j);
      float4 b4 = *(const float4*)(Br + j);
      float2 e0 = sef[j], e1 = sef[j + 1], e2 = sef[j + 2], e3 = sef[j + 3];
      sre += g4.x * e0.x - b4.x * e0.y + g4.y * e1.x - b4.y * e1.y
           + g4.z * e2.x - b4.z * e2.y + g4.w * e3.x - b4.w * e3.y;
      sim += g4.x * e0.y + b4.x * e0.x + g4.y * e1.y + b4.y * e1.x
           + g4.z * e2.y + b4.z * e2.x + g4.w * e3.y + b4.w * e3.x;
    }
    ns_epilogue(b, row, sre, sim, lane, sef, v, th, P, Q, pm, qm, m, nsT);
  }
}

// one 16-node x 16-channel tile of (Tm @ Hin)^T
DEVI float khop_tile(const _Float16* __restrict__ Tm, const _Float16* __restrict__ Hin,
                     int b, int m0, int wave, int lm, int lq, int tid,
                     float (*red)[16][17]) {
  f32x4 acc = {0.f, 0.f, 0.f, 0.f};
  const _Float16* Trow = Tm + ((size_t)b * N_ + m0 + lm) * N_ + wave * 512 + lq * 8;
  const _Float16* Hrow = Hin + ((size_t)b * 16 + lm) * N_ + wave * 512 + lq * 8;
#pragma unroll 4
  for (int k = 0; k < 512; k += 32) {
    f16x8 a = *(const f16x8*)(Trow + k);
    f16x8 hb = *(const f16x8*)(Hrow + k);
    acc = __builtin_amdgcn_mfma_f32_16x16x32_f16(a, hb, acc, 0, 0, 0);
  }
#pragma unroll
  for (int r = 0; r < 4; ++r) red[wave][lq * 4 + r][lm] = acc[r];
  __syncthreads();
  int c = tid >> 4, rr = tid & 15;
  float s = red[0][rr][c] + red[1][rr][c] + red[2][rr][c] + red[3][rr][c];
  __syncthreads();
  return s;
}

// FAST PATH: acc = Tmix @ ns in ONE pass, fused with input projection
__global__ __launch_bounds__(256) void khop_mix_input(
    const _Float16* __restrict__ Tmix, const _Float16* __restrict__ nsT,
    const _Float16* __restrict__ Wint, const float* __restrict__ bin,
    float* __restrict__ x0, _Float16* __restrict__ xh) {
  int b = blockIdx.y, m0 = blockIdx.x * 16;
  int tid = threadIdx.x;
  int wave = tid >> 6, lane = tid & 63;
  int lm = lane & 15, lq = lane >> 4;
  __shared__ float red[4][16][17];
  __shared__ _Float16 in28s[16][32];
  float s = khop_tile(Tmix, nsT, b, m0, wave, lm, lq, tid, red);
  int oc = tid >> 4, orr = tid & 15;
  size_t oidx = ((size_t)b * 16 + oc) * N_ + m0 + orr;
  if (oc < 14) {
    in28s[orr][oc] = nsT[oidx];
    in28s[orr][14 + oc] = f2h(s);
  } else if (oc == 14) {
    in28s[orr][28] = (_Float16)0.f;
    in28s[orr][29] = (_Float16)0.f;
  } else {
    in28s[orr][30] = (_Float16)0.f;
    in28s[orr][31] = (_Float16)0.f;
  }
  __syncthreads();
  f16x8 afrag = *(const f16x8*)(&in28s[lm][lq * 8]);
#pragma unroll
  for (int nt = 0; nt < 4; ++nt) {
    int n0 = wave * 64 + nt * 16;
    f16x8 bfrag = *(const f16x8*)(Wint + (size_t)(n0 + lm) * 32 + lq * 8);
    f32x4 c4 = {0.f, 0.f, 0.f, 0.f};
    c4 = __builtin_amdgcn_mfma_f32_16x16x32_f16(afrag, bfrag, c4, 0, 0, 0);
    float bv = bin[n0 + lm];
#pragma unroll
    for (int rg = 0; rg < 4; ++rg) {
      int rw = lq * 4 + rg;
      float val = c4[rg] + bv;
      size_t o = ((size_t)(b * N_ + m0 + rw)) * 256 + n0 + lm;
      x0[o] = val;
      xh[o] = f2h(val);
    }
  }
}

// FALLBACK PATH: single hop, acc (+)= w * hop
__global__ __launch_bounds__(256) void khop_kernel(const _Float16* __restrict__ Tb,
    const _Float16* __restrict__ HinT, _Float16* __restrict__ HoutT,
    float* __restrict__ accT, float w, int first) {
  int b = blockIdx.y, m0 = blockIdx.x * 16;
  int tid = threadIdx.x;
  int wave = tid >> 6, lane = tid & 63;
  int lm = lane & 15, lq = lane >> 4;
  __shared__ float red[4][16][17];
  float s = khop_tile(Tb, HinT, b, m0, wave, lm, lq, tid, red);
  int c = tid >> 4, r = tid & 15;
  size_t o = ((size_t)b * 16 + c) * N_ + m0 + r;
  if (HoutT) HoutT[o] = f2h(s);
  if (first) accT[o] = w * s; else accT[o] += w * s;
}

// FALLBACK: hop3 + input projection
__global__ __launch_bounds__(256) void khop3_input(const _Float16* __restrict__ Tb,
    const _Float16* __restrict__ HinT, const _Float16* __restrict__ nsT,
    const float* __restrict__ accT, const _Float16* __restrict__ Wint,
    const float* __restrict__ bin, float hw2,
    float* __restrict__ x0, _Float16* __restrict__ xh) {
  int b = blockIdx.y, m0 = blockIdx.x * 16;
  int tid = threadIdx.x;
  int wave = tid >> 6, lane = tid & 63;
  int lm = lane & 15, lq = lane >> 4;
  __shared__ float red[4][16][17];
  __shared__ _Float16 in28s[16][32];
  float s = khop_tile(Tb, HinT, b, m0, wave, lm, lq, tid, red);
  int oc = tid >> 4, orr = tid & 15;
  size_t oidx = ((size_t)b * 16 + oc) * N_ + m0 + orr;
  if (oc < 14) {
    float atot = accT[oidx] + hw2 * s;
    in28s[orr][oc] = nsT[oidx];
    in28s[orr][14 + oc] = f2h(atot);
  } else if (oc == 14) {
    in28s[orr][28] = (_Float16)0.f;
    in28s[orr][29] = (_Float16)0.f;
  } else {
    in28s[orr][30] = (_Float16)0.f;
    in28s[orr][31] = (_Float16)0.f;
  }
  __syncthreads();
  f16x8 afrag = *(const f16x8*)(&in28s[lm][lq * 8]);
#pragma unroll
  for (int nt = 0; nt < 4; ++nt) {
    int n0 = wave * 64 + nt * 16;
    f16x8 bfrag = *(const f16x8*)(Wint + (size_t)(n0 + lm) * 32 + lq * 8);
    f32x4 c4 = {0.f, 0.f, 0.f, 0.f};
    c4 = __builtin_amdgcn_mfma_f32_16x16x32_f16(afrag, bfrag, c4, 0, 0, 0);
    float bv = bin[n0 + lm];
#pragma unroll
    for (int rg = 0; rg < 4; ++rg) {
      int rw = lq * 4 + rg;
      float val = c4[rg] + bv;
      size_t o = ((size_t)(b * N_ + m0 + rw)) * 256 + n0 + lm;
      x0[o] = val;
      xh[o] = f2h(val);
    }
  }
}

// generic C(M,N) = A @ Wt^T + bias (used for QKV)
__global__ __launch_bounds__(256) void gemm_kernel(const _Float16* __restrict__ A,
    const _Float16* __restrict__ Wt, const float* __restrict__ bias,
    float* __restrict__ Cf, _Float16* __restrict__ Ch,
    int N, int K, int relu) {
  int wave = threadIdx.x >> 6, lane = threadIdx.x & 63;
  int wy = wave >> 1, wx = wave & 1;
  int m0 = blockIdx.x * 64 + wy * 32;
  int n0 = blockIdx.y * 64 + wx * 32;
  int lm = lane & 15, lq = lane >> 4;
  f32x4 acc[2][2] = {};
  const _Float16* A0 = A + (size_t)(m0 + lm) * K + lq * 8;
  const _Float16* A1 = A0 + (size_t)16 * K;
  const _Float16* B0 = Wt + (size_t)(n0 + lm) * K + lq * 8;
  const _Float16* B1 = B0 + (size_t)16 * K;
  for (int k = 0; k < K; k += 32) {
    f16x8 a0 = *(const f16x8*)(A0 + k);
    f16x8 a1 = *(const f16x8*)(A1 + k);
    f16x8 b0 = *(const f16x8*)(B0 + k);
    f16x8 b1 = *(const f16x8*)(B1 + k);
    acc[0][0] = __builtin_amdgcn_mfma_f32_16x16x32_f16(a0, b0, acc[0][0], 0, 0, 0);
    acc[0][1] = __builtin_amdgcn_mfma_f32_16x16x32_f16(a0, b1, acc[0][1], 0, 0, 0);
    acc[1][0] = __builtin_amdgcn_mfma_f32_16x16x32_f16(a1, b0, acc[1][0], 0, 0, 0);
    acc[1][1] = __builtin_amdgcn_mfma_f32_16x16x32_f16(a1, b1, acc[1][1], 0, 0, 0);
  }
#pragma unroll
  for (int tm = 0; tm < 2; ++tm)
#pragma unroll
    for (int tn = 0; tn < 2; ++tn) {
      int col = n0 + tn * 16 + lm;
      float bvv = bias ? bias[col] : 0.f;
#pragma unroll
      for (int r = 0; r < 4; ++r) {
        int row = m0 + tm * 16 + lq * 4 + r;
        float val = acc[tm][tn][r] + bvv;
        if (relu) val = fmaxf(val, 0.f);
        size_t o = (size_t)row * N + col;
        if (Cf) Cf[o] = val;
        if (Ch) Ch[o] = f2h(val);
      }
    }
}

// one wave per node; software-pipelined edge gather
__global__ __launch_bounds__(256) void attn_kernel(const _Float16* __restrict__ qkv,
    const int* __restrict__ offs, const int* __restrict__ sp,
    const float* __restrict__ ebp, _Float16* __restrict__ aggh) {
  int node = blockIdx.x * 4 + (threadIdx.x >> 6);
  int lane = threadIdx.x & 63;
  int h = lane >> 3;
  f16x4 qh = *(const f16x4*)(qkv + (size_t)node * 768 + lane * 4);
  float4 q4 = {(float)qh[0], (float)qh[1], (float)qh[2], (float)qh[3]};
  int beg = offs[node], end = offs[node + 1];
  float mx = -3.0e38f, den = 0.f;
  float4 acc = {0.f, 0.f, 0.f, 0.f};
  f16x4 kh_n = {}, vh_n = {};
  float eb_n = 0.f;
  if (beg < end) {
    int s = sp[beg];
    const _Float16* base = qkv + (size_t)s * 768 + lane * 4;
    kh_n = *(const f16x4*)(base + 256);
    vh_n = *(const f16x4*)(base + 512);
    eb_n = ebp[(size_t)beg * 8 + h];
  }
  for (int j = beg; j < end; ++j) {
    f16x4 kh = kh_n, vh = vh_n;
    float ebv = eb_n;
    if (j + 1 < end) {
      int s2 = sp[j + 1];
      const _Float16* b2 = qkv + (size_t)s2 * 768 + lane * 4;
      kh_n = *(const f16x4*)(b2 + 256);
      vh_n = *(const f16x4*)(b2 + 512);
      eb_n = ebp[(size_t)(j + 1) * 8 + h];
    }
    float p = q4.x * (float)kh[0] + q4.y * (float)kh[1]
            + q4.z * (float)kh[2] + q4.w * (float)kh[3];
    p += __shfl_xor(p, 1);
    p += __shfl_xor(p, 2);
    p += __shfl_xor(p, 4);
    float score = p * 0.17677669529663687f + ebv;
    float nm = fmaxf(mx, score);
    float sc = __expf(mx - nm);
    float w = __expf(score - nm);
    den = den * sc + w;
    acc.x = acc.x * sc + w * (float)vh[0];
    acc.y = acc.y * sc + w * (float)vh[1];
    acc.z = acc.z * sc + w * (float)vh[2];
    acc.w = acc.w * sc + w * (float)vh[3];
    mx = nm;
  }
  float inv = den > 0.f ? 1.f / den : 0.f;
  f16x4 o;
  o[0] = f2h(acc.x * inv);
  o[1] = f2h(acc.y * inv);
  o[2] = f2h(acc.z * inv);
  o[3] = f2h(acc.w * inv);
  *(f16x4*)(aggh + (size_t)node * DM_ + lane * 4) = o;
}

// O-proj + residual + LN1 (M-tile 16, grid 512 blocks)
__global__ __launch_bounds__(256) void oproj_ln1(const _Float16* __restrict__ A,
    const _Float16* __restrict__ Wt, const float* __restrict__ bias,
    const float* __restrict__ res, const float* __restrict__ g,
    const float* __restrict__ bb, float* __restrict__ yF,
    _Float16* __restrict__ yH) {
  int m0 = blockIdx.x * 16;
  int wave = threadIdx.x >> 6, lane = threadIdx.x & 63;
  int lm = lane & 15, lq = lane >> 4;
  int n0 = wave * 64;
  f32x4 acc[4] = {};
  const _Float16* Ap = A + (size_t)(m0 + lm) * 256 + lq * 8;
  const _Float16* Bp = Wt + (size_t)(n0 + lm) * 256 + lq * 8;
  for (int k = 0; k < 256; k += 32) {
    f16x8 a0 = *(const f16x8*)(Ap + k);
#pragma unroll
    for (int nt = 0; nt < 4; ++nt) {
      f16x8 bf = *(const f16x8*)(Bp + nt * 16 * 256 + k);
      acc[nt] = __builtin_amdgcn_mfma_f32_16x16x32_f16(a0, bf, acc[nt], 0, 0, 0);
    }
  }
  float val[4][4];
  float rsum[4] = {}, rsq[4] = {};
#pragma unroll
  for (int nt = 0; nt < 4; ++nt) {
    int col = n0 + nt * 16 + lm;
    float bv = bias[col];
#pragma unroll
    for (int rg = 0; rg < 4; ++rg) {
      int row = m0 + lq * 4 + rg;
      float x = acc[nt][rg] + bv + res[(size_t)row * 256 + col];
      val[nt][rg] = x;
      rsum[rg] += x;
      rsq[rg] += x * x;
    }
  }
#pragma unroll
  for (int rg = 0; rg < 4; ++rg)
    for (int off = 1; off < 16; off <<= 1) {
      rsum[rg] += __shfl_xor(rsum[rg], off);
      rsq[rg] += __shfl_xor(rsq[rg], off);
    }
  __shared__ float redS[16][4], redQ[16][4];
  if (lm == 0) {
#pragma unroll
    for (int rg = 0; rg < 4; ++rg) {
      int r = lq * 4 + rg;
      redS[r][wave] = rsum[rg];
      redQ[r][wave] = rsq[rg];
    }
  }
  __syncthreads();
#pragma unroll
  for (int rg = 0; rg < 4; ++rg) {
    int r = lq * 4 + rg;
    float tS = redS[r][0] + redS[r][1] + redS[r][2] + redS[r][3];
    float tQ = redQ[r][0] + redQ[r][1] + redQ[r][2] + redQ[r][3];
    float mu = tS * (1.f / 256.f);
    float var = tQ * (1.f / 256.f) - mu * mu;
    float rs = rsqrtf(var + 1e-5f);
    int row = m0 + r;
#pragma unroll
    for (int nt = 0; nt < 4; ++nt) {
      int col = n0 + nt * 16 + lm;
      float y = g[col] * (val[nt][rg] - mu) * rs + bb[col];
      size_t o = (size_t)row * 256 + col;
      yF[o] = y;
      yH[o] = f2h(y);
    }
  }
}

// fused FFN with LDS overlay: h (phase1) shares LDS with xs/whs/part (phase3)
struct FfnS2 {
  float xs[32][261];
  float whs[3072];
  float part[32][193];
};
union FfnU {
  _Float16 hs[32][1040];
  FfnS2 s2;
};

__global__ __launch_bounds__(512) void ffn_fused(const _Float16* __restrict__ A,
    const _Float16* __restrict__ Wf1t, const float* __restrict__ bf1,
    const _Float16* __restrict__ Wf2t, const float* __restrict__ bf2,
    const float* __restrict__ res, const float* __restrict__ g,
    const float* __restrict__ bb, const float* __restrict__ Wh,
    const float* __restrict__ bh, const float* __restrict__ pm,
    const float* __restrict__ qm, float* __restrict__ v,
    float* __restrict__ th, float* __restrict__ m) {
  constexpr int HP = 1040;
  int m0 = blockIdx.x * 32;
  int tid = threadIdx.x;
  int wave = tid >> 6, lane = tid & 63;
  int lm = lane & 15, lq = lane >> 4;
  __shared__ FfnU u;
  __shared__ float redS[32][8], redQ[32][8];
  // phase 1: h[32][1024] = relu(x @ Wf1 + bf1)
  {
    int n0 = wave * 128;
    f32x4 acc1[2][8] = {};
    const _Float16* Ap = A + (size_t)(m0 + lm) * 256 + lq * 8;
    const _Float16* Bp = Wf1t + (size_t)(n0 + lm) * 256 + lq * 8;
    for (int k = 0; k < 256; k += 32) {
      f16x8 a0 = *(const f16x8*)(Ap + k);
      f16x8 a1 = *(const f16x8*)(Ap + 16 * 256 + k);
#pragma unroll
      for (int nt = 0; nt < 8; ++nt) {
        f16x8 bf = *(const f16x8*)(Bp + nt * 16 * 256 + k);
        acc1[0][nt] = __builtin_amdgcn_mfma_f32_16x16x32_f16(a0, bf, acc1[0][nt], 0, 0, 0);
        acc1[1][nt] = __builtin_amdgcn_mfma_f32_16x16x32_f16(a1, bf, acc1[1][nt], 0, 0, 0);
      }
    }
#pragma unroll
    for (int mt = 0; mt < 2; ++mt)
#pragma unroll
      for (int nt = 0; nt < 8; ++nt) {
        int col = n0 + nt * 16 + lm;
        float bv = bf1[col];
#pragma unroll
        for (int rg = 0; rg < 4; ++rg) {
          int rloc = mt * 16 + lq * 4 + rg;
          u.hs[rloc][col] = f2h(fmaxf(acc1[mt][nt][rg] + bv, 0.f));
        }
      }
  }
  __syncthreads();
  // phase 2: y[32][256] = h @ Wf2 + bf2 + res, LN  (reads u.hs)
  float val[2][2][4];
  float rsum[2][4] = {}, rsq[2][4] = {};
  {
    int n0 = wave * 32;
    f32x4 acc2[2][2] = {};
    const _Float16* Bp = Wf2t + (size_t)(n0 + lm) * 1024 + lq * 8;
    for (int k = 0; k < 1024; k += 32) {
      f16x8 a0 = *(const f16x8*)(&u.hs[lm][k + lq * 8]);
      f16x8 a1 = *(const f16x8*)(&u.hs[16 + lm][k + lq * 8]);
      f16x8 b0 = *(const f16x8*)(Bp + k);
      f16x8 b1 = *(const f16x8*)(Bp + 16 * 1024 + k);
      acc2[0][0] = __builtin_amdgcn_mfma_f32_16x16x32_f16(a0, b0, acc2[0][0], 0, 0, 0);
      acc2[0][1] = __builtin_amdgcn_mfma_f32_16x16x32_f16(a0, b1, acc2[0][1], 0, 0, 0);
      acc2[1][0] = __builtin_amdgcn_mfma_f32_16x16x32_f16(a1, b0, acc2[1][0], 0, 0, 0);
      acc2[1][1] = __builtin_amdgcn_mfma_f32_16x16x32_f16(a1, b1, acc2[1][1], 0, 0, 0);
    }
#pragma unroll
    for (int mt = 0; mt < 2; ++mt)
#pragma unroll
      for (int nt = 0; nt < 2; ++nt) {
        int col = n0 + nt * 16 + lm;
        float bv = bf2[col];
#pragma unroll
        for (int rg = 0; rg < 4; ++rg) {
          int row = m0 + mt * 16 + lq * 4 + rg;
          float x = acc2[mt][nt][rg] + bv + res[(size_t)row * 256 + col];
          val[mt][nt][rg] = x;
          rsum[mt][rg] += x;
          rsq[mt][rg] += x * x;
        }
      }
  }
#pragma unroll
  for (int mt = 0; mt < 2; ++mt)
#pragma unroll
    for (int rg = 0; rg < 4; ++rg)
      for (int off = 1; off < 16; off <<= 1) {
        rsum[mt][rg] += __shfl_xor(rsum[mt][rg], off);
        rsq[mt][rg] += __shfl_xor(rsq[mt][rg], off);
      }
  if (lm == 0) {
#pragma unroll
    for (int mt = 0; mt < 2; ++mt)
#pragma unroll
      for (int rg = 0; rg < 4; ++rg) {
        int r = mt * 16 + lq * 4 + rg;
        redS[r][wave] = rsum[mt][rg];
        redQ[r][wave] = rsq[mt][rg];
      }
  }
  __syncthreads();  // all hs reads done; s2 region now safe to write
  for (int i = tid; i < 3072; i += 512) u.s2.whs[i] = Wh[i];
#pragma unroll
  for (int mt = 0; mt < 2; ++mt)
#pragma unroll
    for (int rg = 0; rg < 4; ++rg) {
      int r = mt * 16 + lq * 4 + rg;
      float tS = 0.f, tQ = 0.f;
#pragma unroll
      for (int w = 0; w < 8; ++w) { tS += redS[r][w]; tQ += redQ[r][w]; }
      float mu = tS * (1.f / 256.f);
      float var = tQ * (1.f / 256.f) - mu * mu;
      float rs = rsqrtf(var + 1e-5f);
#pragma unroll
      for (int nt = 0; nt < 2; ++nt) {
        int col = wave * 32 + nt * 16 + lm;
        u.s2.xs[r][col] = g[col] * (val[mt][nt][rg] - mu) * rs + bb[col];
      }
    }
  __syncthreads();
  // heads: 12 dots per row over 256 cols (16 groups x 16 cols)
  {
    int rw = tid & 31, grp = tid >> 5;
    float pa[12] = {};
    for (int c = 0; c < 16; ++c) {
      int col = grp * 16 + c;
      float xv = u.s2.xs[rw][col];
#pragma unroll
      for (int o = 0; o < 12; ++o) pa[o] += xv * u.s2.whs[col * 12 + o];
    }
#pragma unroll
    for (int o = 0; o < 12; ++o) u.s2.part[rw][grp * 12 + o] = pa[o];
  }
  __syncthreads();
  if (tid < 32) {
    int node = m0 + tid;
    float tot[12];
#pragma unroll
    for (int o = 0; o < 12; ++o) {
      float s = bh[o];
#pragma unroll
      for (int grp = 0; grp < 16; ++grp) s += u.s2.part[tid][grp * 12 + o];
      tot[o] = s;
    }
    th[node] += tot[0] * pm[node];
    v[node] += tot[1] * qm[node];
#pragma unroll
    for (int d = 0; d < 10; ++d) m[(size_t)node * 10 + d] = tot[2 + d];
  }
}

__global__ void out_kernel(const float* __restrict__ v, const float* __restrict__ th,
                           float* __restrict__ out) {
  int t = blockIdx.x * blockDim.x + threadIdx.x;
  if (t >= BN_) return;
  out[2 * t] = v[t];
  out[2 * t + 1] = th[t];
}

// ---------------- launcher ----------------

extern "C" void kernel_launch(void* const* d_in, const int* in_sizes, int n_in,
                              void* d_out, int out_size, void* d_ws, size_t ws_size,
                              hipStream_t stream) {
  const int* bus = (const int*)d_in[0];
  const int* ei = (const int*)d_in[1];
  const float* G = (const float*)d_in[2];
  const float* Bm = (const float*)d_in[3];
  const float* P = (const float*)d_in[4];
  const float* Q = (const float*)d_in[5];
  const float* V0 = (const float*)d_in[6];
  const float* efeat = (const float*)d_in[7];
  const float* Win = (const float*)d_in[8];
  const float* bin = (const float*)d_in[9];
  const float* Wq = (const float*)d_in[10];
  const float* bq = (const float*)d_in[11];
  const float* Wk = (const float*)d_in[12];
  const float* bk = (const float*)d_in[13];
  const float* Wv = (const float*)d_in[14];
  const float* bv = (const float*)d_in[15];
  const float* Wo = (const float*)d_in[16];
  const float* bo = (const float*)d_in[17];
  const float* We = (const float*)d_in[18];
  const float* be = (const float*)d_in[19];
  const float* g1 = (const float*)d_in[20];
  const float* b1 = (const float*)d_in[21];
  const float* g2 = (const float*)d_in[22];
  const float* b2 = (const float*)d_in[23];
  const float* Wf1 = (const float*)d_in[24];
  const float* bf1 = (const float*)d_in[25];
  const float* Wf2 = (const float*)d_in[26];
  const float* bf2 = (const float*)d_in[27];
  const float* Wth = (const float*)d_in[28];
  const float* bth = (const float*)d_in[29];
  const float* Wvh = (const float*)d_in[30];
  const float* bvh = (const float*)d_in[31];
  const float* Wm = (const float*)d_in[32];
  const float* bm = (const float*)d_in[33];
  float* out = (float*)d_out;

  char* p = (char*)d_ws;
  auto alloc = [&](size_t bytes) -> void* {
    void* r = (void*)p;
    p += (bytes + 255) & ~(size_t)255;
    return r;
  };
  _Float16* Tb = (_Float16*)alloc((size_t)BN_ * N_ * 2);     // 33.5 MB
  _Float16* nsT = (_Float16*)alloc((size_t)B_ * 16 * N_ * 2);
  _Float16* H1 = (_Float16*)alloc((size_t)B_ * 16 * N_ * 2);
  _Float16* H2 = (_Float16*)alloc((size_t)B_ * 16 * N_ * 2);
  float* accT = (float*)alloc((size_t)B_ * 16 * N_ * 4);
  _Float16* qkvh = (_Float16*)alloc((size_t)BN_ * 768 * 2);
  float* x0 = (float*)alloc((size_t)BN_ * 256 * 4);
  float* x1 = (float*)alloc((size_t)BN_ * 256 * 4);
  _Float16* xhA = (_Float16*)alloc((size_t)BN_ * 256 * 2);
  _Float16* xhB = (_Float16*)alloc((size_t)BN_ * 256 * 2);
  float* eb = (float*)alloc((size_t)BE_ * 8 * 4);
  float* ebp = (float*)alloc((size_t)BE_ * 8 * 4);
  int* srcf = (int*)alloc((size_t)BE_ * 4);
  int* dstf = (int*)alloc((size_t)BE_ * 4);
  int* sp = (int*)alloc((size_t)BE_ * 4);
  int* counts = (int*)alloc((size_t)BN_ * 4);
  int* offs = (int*)alloc((size_t)(BN_ + 1) * 4);
  int* cursor = (int*)alloc((size_t)BN_ * 4);
  int* perm = (int*)alloc((size_t)BE_ * 4);
  _Float16* Wqkvt = (_Float16*)alloc(768 * 256 * 2);
  _Float16* Wot = (_Float16*)alloc(256 * 256 * 2);
  _Float16* Wf1t = (_Float16*)alloc(1024 * 256 * 2);
  _Float16* Wf2t = (_Float16*)alloc(256 * 1024 * 2);
  _Float16* Wint = (_Float16*)alloc(256 * 32 * 2);
  float* Wheads = (float*)alloc(30 * 3072 * 4);
  float* bheads = (float*)alloc(30 * 12 * 4);
  float* bqkv = (float*)alloc(768 * 4);
  float* v = (float*)alloc((size_t)BN_ * 4);
  float* th = (float*)alloc((size_t)BN_ * 4);
  float* pm = (float*)alloc((size_t)BN_ * 4);
  float* qm = (float*)alloc((size_t)BN_ * 4);
  float* m = (float*)alloc((size_t)BN_ * 10 * 4);

  size_t nn2 = (size_t)B_ * N_ * N_ * 2;  // 33.5 MB
  size_t used = (size_t)(p - (char*)d_ws);
  bool tmix_ok = (used + 3 * (nn2 + 256) <= ws_size);
  _Float16 *Tt = nullptr, *T2 = nullptr, *Tmix = nullptr;
  if (tmix_ok) {
    Tt = (_Float16*)alloc(nn2);
    T2 = (_Float16*)alloc(nn2);
    Tmix = (_Float16*)alloc(nn2);
  }
  used = (size_t)(p - (char*)d_ws);
  bool f16gb = (used + 2 * (nn2 + 256) <= ws_size);
  _Float16 *Gh = nullptr, *Bh = nullptr;
  if (f16gb) {
    Gh = (_Float16*)alloc(nn2);
    Bh = (_Float16*)alloc(nn2);
  }

  double hwd[3], z = 0.0;
  for (int i = 0; i < 3; ++i) {
    hwd[i] = exp(-((double)(i + 1) * (i + 1)) / (2.0 * 1.5 * 1.5));
    z += hwd[i];
  }
  float hw0 = (float)(hwd[0] / z), hw1 = (float)(hwd[1] / z), hw2 = (float)(hwd[2] / z);

  init_state<<<32, 256, 0, stream>>>(bus, V0, v, th, m, pm, qm, counts);
  build_T_cast<<<8192, 256, 0, stream>>>(G, Bm, Tb, Gh, Bh);
  if (tmix_ok) {
    transpose16<<<dim3(32, 32, 4), 256, 0, stream>>>(Tb, Tt);
    // T2 = T @ T
    gemm_bat<<<dim3(16, 16, 4), 256, 0, stream>>>(Tb, Tt, T2,
        (const _Float16*)nullptr, (const _Float16*)nullptr, 0.f, 0.f, 0.f);
    // Tmix = hw0*T + hw1*T2 + hw2*(T2 @ T)
    gemm_bat<<<dim3(16, 16, 4), 256, 0, stream>>>(T2, Tt, Tmix, Tb, T2,
                                                  hw0, hw1, hw2);
  }
  edge_prep<<<BE_ / 256, 256, 0, stream>>>(ei, efeat, We, be, eb, srcf, dstf, counts);
  scan_kernel<<<1, 256, 0, stream>>>(counts, offs, cursor);
  scatter_kernel<<<BE_ / 256, 256, 0, stream>>>(dstf, cursor, perm);
  edge_reorder<<<BE_ / 256, 256, 0, stream>>>(perm, srcf, eb, sp, ebp);
  prep_weights<<<(887912 + 255) / 256, 256, 0, stream>>>(
      Wq, bq, Wk, bk, Wv, bv, Wo, Wf1, Wf2, Wth, bth, Wvh, bvh, Wm, bm, Win,
      Wqkvt, bqkv, Wot, Wf1t, Wf2t, Wheads, bheads, Wint);

  for (int k = 0; k < 30; ++k) {
    if (f16gb)
      matvec_ns_f16<<<dim3(128, 4), 256, 0, stream>>>(Gh, Bh, v, th, P, Q, pm, qm,
                                                      m, nsT);
    else
      matvec_ns_f32<<<dim3(128, 4), 256, 0, stream>>>(G, Bm, v, th, P, Q, pm, qm,
                                                      m, nsT);
    if (tmix_ok) {
      khop_mix_input<<<dim3(128, 4), 256, 0, stream>>>(Tmix, nsT, Wint, bin,
                                                       x0, xhA);
    } else {
      khop_kernel<<<dim3(128, 4), 256, 0, stream>>>(Tb, nsT, H1, accT, hw0, 1);
      khop_kernel<<<dim3(128, 4), 256, 0, stream>>>(Tb, H1, H2, accT, hw1, 0);
      khop3_input<<<dim3(128, 4), 256, 0, stream>>>(Tb, H2, nsT, accT, Wint, bin,
                                                    hw2, x0, xhA);
    }
    gemm_kernel<<<dim3(128, 12), 256, 0, stream>>>(xhA, Wqkvt, bqkv, nullptr, qkvh,
                                                   768, 256, 0);
    attn_kernel<<<2048, 256, 0, stream>>>(qkvh, offs, sp, ebp, xhB);
    oproj_ln1<<<512, 256, 0, stream>>>(xhB, Wot, bo, x0, g1, b1, x1, xhA);
    ffn_fused<<<256, 512, 0, stream>>>(xhA, Wf1t, bf1, Wf2t, bf2, x1, g2, b2,
                                       Wheads + k * 3072, bheads + k * 12,
                                       pm, qm, v, th, m);
  }
  out_kernel<<<32, 256, 0, stream>>>(v, th, out);
}

// Round 7
// 3852.334 us; speedup vs baseline: 1.9969x; 1.1987x over previous
//
#include <hip/hip_runtime.h>
#include <math.h>

typedef _Float16 f16x8 __attribute__((ext_vector_type(8)));
typedef _Float16 f16x4 __attribute__((ext_vector_type(4)));
typedef float f32x4 __attribute__((ext_vector_type(4)));

constexpr int B_ = 4, N_ = 2048, E_ = 16384;
constexpr int D_ = 10, DM_ = 256, NH_ = 8, FE_ = 9;
constexpr int BN_ = B_ * N_;   // 8192
constexpr int BE_ = B_ * E_;   // 65536

#define DEVI __device__ __forceinline__

DEVI _Float16 f2h(float f) { return (_Float16)f; }

// ---------------- setup kernels ----------------

__global__ void init_state(const int* __restrict__ bus, const float* __restrict__ V0,
                           float* v, float* th, float* m, float* pm, float* qm,
                           int* counts) {
  int t = blockIdx.x * blockDim.x + threadIdx.x;
  if (t >= BN_) return;
  int bt = bus[t];
  pm[t] = (bt == 1) ? 0.f : 1.f;
  qm[t] = (bt == 1 || bt == 2) ? 0.f : 1.f;
  v[t] = V0[2 * t];
  th[t] = V0[2 * t + 1];
  for (int d = 0; d < D_; ++d) m[(size_t)t * D_ + d] = 0.f;
  counts[t] = 0;
}

// one pass over G,Bm: write T (row-normalized adjacency) + fp16 copies of G,Bm
__global__ __launch_bounds__(256) void build_T_cast(const float* __restrict__ G,
    const float* __restrict__ Bm, _Float16* __restrict__ Tb,
    _Float16* __restrict__ Gh, _Float16* __restrict__ Bh) {
  int row = blockIdx.x;
  int i = row & (N_ - 1);
  const float* Gr = G + (size_t)row * N_;
  const float* Br = Bm + (size_t)row * N_;
  float a[8];
  float s = 0.f;
#pragma unroll
  for (int u = 0; u < 8; ++u) {
    int j = threadIdx.x + u * 256;
    float g = Gr[j], b = Br[j];
    if (Gh) { Gh[(size_t)row * N_ + j] = f2h(g); Bh[(size_t)row * N_ + j] = f2h(b); }
    float av = sqrtf(g * g + b * b);
    if (j == i) av = 0.f;
    a[u] = av;
    s += av;
  }
  __shared__ float red[4];
  for (int off = 32; off; off >>= 1) s += __shfl_down(s, off);
  int lane = threadIdx.x & 63, wave = threadIdx.x >> 6;
  if (lane == 0) red[wave] = s;
  __syncthreads();
  float tot = red[0] + red[1] + red[2] + red[3];
  float inv = 1.f / fmaxf(tot, 1e-12f);
#pragma unroll
  for (int u = 0; u < 8; ++u) {
    int j = threadIdx.x + u * 256;
    Tb[(size_t)row * N_ + j] = f2h(a[u] * inv);
  }
}

// 64x64 tiled fp16 transpose (per batch)
__global__ __launch_bounds__(256) void transpose16(const _Float16* __restrict__ in,
                                                   _Float16* __restrict__ out) {
  __shared__ float tile[64][65];
  int b = blockIdx.z;
  const _Float16* A = in + (size_t)b * N_ * N_;
  _Float16* O = out + (size_t)b * N_ * N_;
  int r0 = blockIdx.y * 64, c0 = blockIdx.x * 64;
  int tc = threadIdx.x & 63, tg = threadIdx.x >> 6;
#pragma unroll
  for (int i = 0; i < 16; ++i) {
    int r = tg * 16 + i;
    tile[r][tc] = (float)A[(size_t)(r0 + r) * N_ + c0 + tc];
  }
  __syncthreads();
#pragma unroll
  for (int i = 0; i < 16; ++i) {
    int r = tg * 16 + i;
    O[(size_t)(c0 + r) * N_ + r0 + tc] = f2h(tile[tc][r]);
  }
}

// LDS-staged GEMM core: C128x128 tile = A(128,K) @ Bt(128,K)^T
// 256 threads / 4 waves (2x2), BK=64, coalesced staging + reg prefetch.
DEVI void gemm_core(const _Float16* __restrict__ A, const _Float16* __restrict__ Bt,
                    int lda, int ldb, int K, int m0, int n0, int tid,
                    _Float16 (*As)[72], _Float16 (*Bs)[72], f32x4 (*acc)[4]) {
  int wave = tid >> 6, lane = tid & 63;
  int wy = wave >> 1, wx = wave & 1;
  int lm = lane & 15, lq = lane >> 4;
  int srow = tid >> 1, sh = (tid & 1) * 32;   // staging: row 0..127, 32-fp16 half
  const _Float16* Ag = A + (size_t)(m0 + srow) * lda + sh;
  const _Float16* Bg = Bt + (size_t)(n0 + srow) * ldb + sh;
  f16x8 a4[4], b4[4];
#pragma unroll
  for (int c = 0; c < 4; ++c) {
    a4[c] = *(const f16x8*)(Ag + c * 8);
    b4[c] = *(const f16x8*)(Bg + c * 8);
  }
  for (int kt = 0; kt < K; kt += 64) {
    __syncthreads();
#pragma unroll
    for (int c = 0; c < 4; ++c) {
      *(f16x8*)(&As[srow][sh + c * 8]) = a4[c];
      *(f16x8*)(&Bs[srow][sh + c * 8]) = b4[c];
    }
    __syncthreads();
    if (kt + 64 < K) {
#pragma unroll
      for (int c = 0; c < 4; ++c) {
        a4[c] = *(const f16x8*)(Ag + kt + 64 + c * 8);
        b4[c] = *(const f16x8*)(Bg + kt + 64 + c * 8);
      }
    }
#pragma unroll
    for (int s = 0; s < 2; ++s) {
      f16x8 af[4], bf[4];
#pragma unroll
      for (int i = 0; i < 4; ++i) {
        af[i] = *(const f16x8*)(&As[wy * 64 + i * 16 + lm][s * 32 + lq * 8]);
        bf[i] = *(const f16x8*)(&Bs[wx * 64 + i * 16 + lm][s * 32 + lq * 8]);
      }
#pragma unroll
      for (int mi = 0; mi < 4; ++mi)
#pragma unroll
        for (int ni = 0; ni < 4; ++ni)
          acc[mi][ni] = __builtin_amdgcn_mfma_f32_16x16x32_f16(af[mi], bf[ni],
                                                               acc[mi][ni], 0, 0, 0);
    }
  }
}

// batched C = A @ Bt^T via LDS-staged core; epilogue: out = w3*C + w1*M1 + w2*M2
__global__ __launch_bounds__(256) void gemm_bat2(const _Float16* __restrict__ A,
    const _Float16* __restrict__ Bt, _Float16* __restrict__ Cout,
    const _Float16* __restrict__ M1, const _Float16* __restrict__ M2,
    float w1, float w2, float w3) {
  __shared__ _Float16 As[128][72], Bs[128][72];
  int b = blockIdx.z;
  size_t base = (size_t)b * N_ * N_;
  int m0 = blockIdx.x * 128, n0 = blockIdx.y * 128;
  f32x4 acc[4][4] = {};
  gemm_core(A + base, Bt + base, N_, N_, N_, m0, n0, threadIdx.x, As, Bs, acc);
  int wave = threadIdx.x >> 6, lane = threadIdx.x & 63;
  int wy = wave >> 1, wx = wave & 1;
  int lm = lane & 15, lq = lane >> 4;
#pragma unroll
  for (int mi = 0; mi < 4; ++mi)
#pragma unroll
    for (int ni = 0; ni < 4; ++ni) {
      int col = n0 + wx * 64 + ni * 16 + lm;
#pragma unroll
      for (int r = 0; r < 4; ++r) {
        int row = m0 + wy * 64 + mi * 16 + lq * 4 + r;
        size_t o = base + (size_t)row * N_ + col;
        float val = acc[mi][ni][r];
        if (M1) val = w3 * val + w1 * (float)M1[o] + w2 * (float)M2[o];
        Cout[o] = f2h(val);
      }
    }
}

// QKV projection via LDS-staged core: C(8192,768) = xh(8192,256) @ Wqkvt^T + bias
__global__ __launch_bounds__(256) void qkv_ldst(const _Float16* __restrict__ A,
    const _Float16* __restrict__ Wt, const float* __restrict__ bias,
    _Float16* __restrict__ C) {
  __shared__ _Float16 As[128][72], Bs[128][72];
  int m0 = blockIdx.x * 128, n0 = blockIdx.y * 128;
  f32x4 acc[4][4] = {};
  gemm_core(A, Wt, 256, 256, 256, m0, n0, threadIdx.x, As, Bs, acc);
  int wave = threadIdx.x >> 6, lane = threadIdx.x & 63;
  int wy = wave >> 1, wx = wave & 1;
  int lm = lane & 15, lq = lane >> 4;
#pragma unroll
  for (int mi = 0; mi < 4; ++mi)
#pragma unroll
    for (int ni = 0; ni < 4; ++ni) {
      int col = n0 + wx * 64 + ni * 16 + lm;
      float bv = bias[col];
#pragma unroll
      for (int r = 0; r < 4; ++r) {
        int row = m0 + wy * 64 + mi * 16 + lq * 4 + r;
        C[(size_t)row * 768 + col] = f2h(acc[mi][ni][r] + bv);
      }
    }
}

__global__ void edge_prep(const int* __restrict__ ei, const float* __restrict__ efeat,
    const float* __restrict__ We, const float* __restrict__ be,
    float* __restrict__ eb, int* __restrict__ srcf, int* __restrict__ dstf,
    int* __restrict__ counts) {
  int t = blockIdx.x * blockDim.x + threadIdx.x;
  if (t >= BE_) return;
  int b = t / E_, e = t - b * E_;
  int src = ei[(size_t)b * 2 * E_ + e];
  int dst = ei[(size_t)b * 2 * E_ + E_ + e];
  srcf[t] = src + b * N_;
  int df = dst + b * N_;
  dstf[t] = df;
  atomicAdd(&counts[df], 1);
  float fv[FE_];
#pragma unroll
  for (int f = 0; f < FE_; ++f) fv[f] = efeat[(size_t)t * FE_ + f];
#pragma unroll
  for (int h = 0; h < NH_; ++h) {
    float s = be[h];
#pragma unroll
    for (int f = 0; f < FE_; ++f) s += fv[f] * We[f * NH_ + h];
    eb[(size_t)t * NH_ + h] = s;
  }
}

__global__ void scan_kernel(const int* __restrict__ counts, int* __restrict__ offs,
                            int* __restrict__ cursor) {
  __shared__ int part[256];
  int t = threadIdx.x;
  int base = t * 32;
  int loc[32];
  int s = 0;
#pragma unroll
  for (int i = 0; i < 32; ++i) { loc[i] = counts[base + i]; s += loc[i]; }
  part[t] = s;
  __syncthreads();
  for (int off = 1; off < 256; off <<= 1) {
    int vv = (t >= off) ? part[t - off] : 0;
    __syncthreads();
    part[t] += vv;
    __syncthreads();
  }
  int run = part[t] - s;
#pragma unroll
  for (int i = 0; i < 32; ++i) {
    offs[base + i] = run;
    cursor[base + i] = run;
    run += loc[i];
  }
  if (t == 255) offs[BN_] = run;
}

__global__ void scatter_kernel(const int* __restrict__ dstf, int* cursor,
                               int* __restrict__ perm) {
  int t = blockIdx.x * blockDim.x + threadIdx.x;
  if (t >= BE_) return;
  int d = dstf[t];
  int pos = atomicAdd(&cursor[d], 1);
  perm[pos] = t;
}

__global__ void edge_reorder(const int* __restrict__ perm, const int* __restrict__ srcf,
                             const float* __restrict__ eb, int* __restrict__ sp,
                             float* __restrict__ ebp) {
  int j = blockIdx.x * 256 + threadIdx.x;
  if (j >= BE_) return;
  int e = perm[j];
  sp[j] = srcf[e];
#pragma unroll
  for (int h = 0; h < NH_; ++h) ebp[(size_t)j * 8 + h] = eb[(size_t)e * 8 + h];
}

__global__ void prep_weights(const float* Wq, const float* bq, const float* Wk,
    const float* bk, const float* Wv, const float* bvv, const float* Wo,
    const float* Wf1, const float* Wf2, const float* Wth, const float* bth,
    const float* Wvh, const float* bvh, const float* Wm, const float* bm,
    const float* Win,
    _Float16* Wqkvt, float* bqkv, _Float16* Wot,
    _Float16* Wf1t, _Float16* Wf2t, float* Wheads, float* bheads,
    _Float16* Wint) {
  int i = blockIdx.x * blockDim.x + threadIdx.x;
  if (i < 768 * 256) {
    int n = i >> 8, kk = i & 255;
    float val = n < 256 ? Wq[kk * 256 + n]
              : n < 512 ? Wk[kk * 256 + (n - 256)] : Wv[kk * 256 + (n - 512)];
    Wqkvt[n * 256 + kk] = f2h(val);
    return;
  }
  i -= 768 * 256;
  if (i < 256 * 256) {
    int n = i >> 8, kk = i & 255;
    Wot[n * 256 + kk] = f2h(Wo[kk * 256 + n]);
    return;
  }
  i -= 256 * 256;
  if (i < 1024 * 256) {
    int n = i >> 8, kk = i & 255;
    Wf1t[n * 256 + kk] = f2h(Wf1[kk * 1024 + n]);
    return;
  }
  i -= 1024 * 256;
  if (i < 256 * 1024) {
    int n = i >> 10, kk = i & 1023;
    Wf2t[n * 1024 + kk] = f2h(Wf2[kk * 256 + n]);
    return;
  }
  i -= 256 * 1024;
  if (i < 30 * 3072) {
    int k = i / 3072, j = i - k * 3072;
    int row = j / 12, o = j - row * 12;
    float val = o == 0 ? Wth[k * 256 + row]
              : o == 1 ? Wvh[k * 256 + row] : Wm[k * 2560 + row * 10 + (o - 2)];
    Wheads[k * 3072 + j] = val;
    return;
  }
  i -= 30 * 3072;
  if (i < 360) {
    int k = i / 12, o = i - k * 12;
    bheads[i] = o == 0 ? bth[k] : o == 1 ? bvh[k] : bm[k * 10 + (o - 2)];
    return;
  }
  i -= 360;
  if (i < 768) {
    bqkv[i] = i < 256 ? bq[i] : i < 512 ? bk[i - 256] : bvv[i - 512];
    return;
  }
  i -= 768;
  if (i < 256 * 32) {
    int n = i >> 5, kk = i & 31;
    Wint[n * 32 + kk] = (kk < 28) ? f2h(Win[kk * 256 + n]) : (_Float16)0.f;
  }
}

// ---------------- per-step kernels ----------------

DEVI void ns_epilogue(int b, int row, float sre, float sim, int lane,
                      const float2* sef, const float* v, const float* th,
                      const float* P, const float* Q, const float* pm,
                      const float* qm, const float* m, _Float16* nsT) {
  for (int off = 1; off < 64; off <<= 1) {
    sre += __shfl_xor(sre, off);
    sim += __shfl_xor(sim, off);
  }
  if (lane < 16) {
    int node = b * N_ + row;
    float val;
    if (lane == 0) val = v[node];
    else if (lane == 1) val = th[node];
    else if (lane == 2) {
      float2 ef = sef[row];
      val = (P[node] - (ef.x * sre + ef.y * sim)) * pm[node];
    } else if (lane == 3) {
      float2 ef = sef[row];
      val = (Q[node] - (ef.y * sre - ef.x * sim)) * qm[node];
    } else if (lane < 14) val = m[(size_t)node * 10 + (lane - 4)];
    else val = 0.f;
    nsT[(size_t)b * 16 * N_ + (size_t)lane * N_ + row] = f2h(val);
  }
}

__global__ __launch_bounds__(256) void matvec_ns_f16(const _Float16* __restrict__ Gh,
    const _Float16* __restrict__ Bh, const float* __restrict__ v,
    const float* __restrict__ th, const float* __restrict__ P,
    const float* __restrict__ Q, const float* __restrict__ pm,
    const float* __restrict__ qm, const float* __restrict__ m,
    _Float16* __restrict__ nsT) {
  int b = blockIdx.y;
  __shared__ float2 sef[N_];
  for (int i = threadIdx.x; i < N_; i += 256) {
    float vv = v[b * N_ + i], tt = th[b * N_ + i];
    float sn, cs;
    __sincosf(tt, &sn, &cs);
    sef[i] = make_float2(vv * cs, vv * sn);
  }
  __syncthreads();
  int wave = threadIdx.x >> 6, lane = threadIdx.x & 63;
  for (int rr = 0; rr < 4; ++rr) {
    int row = blockIdx.x * 16 + wave * 4 + rr;
    const _Float16* Gr = Gh + ((size_t)b * N_ + row) * N_;
    const _Float16* Br = Bh + ((size_t)b * N_ + row) * N_;
    float sre = 0.f, sim = 0.f;
#pragma unroll
    for (int jj = 0; jj < 4; ++jj) {
      int j = lane * 8 + jj * 512;
      f16x8 g8 = *(const f16x8*)(Gr + j);
      f16x8 b8 = *(const f16x8*)(Br + j);
#pragma unroll
      for (int u = 0; u < 8; ++u) {
        float g = (float)g8[u], bb = (float)b8[u];
        float2 ef = sef[j + u];
        sre += g * ef.x - bb * ef.y;
        sim += g * ef.y + bb * ef.x;
      }
    }
    ns_epilogue(b, row, sre, sim, lane, sef, v, th, P, Q, pm, qm, m, nsT);
  }
}

__global__ __launch_bounds__(256) void matvec_ns_f32(const float* __restrict__ G,
    const float* __restrict__ Bm, const float* __restrict__ v,
    const float* __restrict__ th, const float* __restrict__ P,
    const float* __restrict__ Q, const float* __restrict__ pm,
    const float* __restrict__ qm, const float* __restrict__ m,
    _Float16* __restrict__ nsT) {
  int b = blockIdx.y;
  __shared__ float2 sef[N_];
  for (int i = threadIdx.x; i < N_; i += 256) {
    float vv = v[b * N_ + i], tt = th[b * N_ + i];
    float sn, cs;
    __sincosf(tt, &sn, &cs);
    sef[i] = make_float2(vv * cs, vv * sn);
  }
  __syncthreads();
  int wave = threadIdx.x >> 6, lane = threadIdx.x & 63;
  for (int rr = 0; rr < 4; ++rr) {
    int row = blockIdx.x * 16 + wave * 4 + rr;
    const float* Gr = G + ((size_t)b * N_ + row) * N_;
    const float* Br = Bm + ((size_t)b * N_ + row) * N_;
    float sre = 0.f, sim = 0.f;
#pragma unroll
    for (int jj = 0; jj < 8; ++jj) {
      int j = lane * 4 + jj * 256;
      float4 g4 = *(const float4*)(Gr + j);
      float4 b4 = *(const float4*)(Br + j);
      float2 e0 = sef[j], e1 = sef[j + 1], e2 = sef[j + 2], e3 = sef[j + 3];
      sre += g4.x * e0.x - b4.x * e0.y + g4.y * e1.x - b4.y * e1.y
           + g4.z * e2.x - b4.z * e2.y + g4.w * e3.x - b4.w * e3.y;
      sim += g4.x * e0.y + b4.x * e0.x + g4.y * e1.y + b4.y * e1.x
           + g4.z * e2.y + b4.z * e2.x + g4.w * e3.y + b4.w * e3.x;
    }
    ns_epilogue(b, row, sre, sim, lane, sef, v, th, P, Q, pm, qm, m, nsT);
  }
}

// one 16-node x 16-channel tile of (Tm @ Hin)^T
DEVI float khop_tile(const _Float16* __restrict__ Tm, const _Float16* __restrict__ Hin,
                     int b, int m0, int wave, int lm, int lq, int tid,
                     float (*red)[16][17]) {
  f32x4 acc = {0.f, 0.f, 0.f, 0.f};
  const _Float16* Trow = Tm + ((size_t)b * N_ + m0 + lm) * N_ + wave * 512 + lq * 8;
  const _Float16* Hrow = Hin + ((size_t)b * 16 + lm) * N_ + wave * 512 + lq * 8;
#pragma unroll 4
  for (int k = 0; k < 512; k += 32) {
    f16x8 a = *(const f16x8*)(Trow + k);
    f16x8 hb = *(const f16x8*)(Hrow + k);
    acc = __builtin_amdgcn_mfma_f32_16x16x32_f16(a, hb, acc, 0, 0, 0);
  }
#pragma unroll
  for (int r = 0; r < 4; ++r) red[wave][lq * 4 + r][lm] = acc[r];
  __syncthreads();
  int c = tid >> 4, rr = tid & 15;
  float s = red[0][rr][c] + red[1][rr][c] + red[2][rr][c] + red[3][rr][c];
  __syncthreads();
  return s;
}

// FAST PATH: acc = Tmix @ ns in ONE pass, fused with input projection
__global__ __launch_bounds__(256) void khop_mix_input(
    const _Float16* __restrict__ Tmix, const _Float16* __restrict__ nsT,
    const _Float16* __restrict__ Wint, const float* __restrict__ bin,
    float* __restrict__ x0, _Float16* __restrict__ xh) {
  int b = blockIdx.y, m0 = blockIdx.x * 16;
  int tid = threadIdx.x;
  int wave = tid >> 6, lane = tid & 63;
  int lm = lane & 15, lq = lane >> 4;
  __shared__ float red[4][16][17];
  __shared__ _Float16 in28s[16][32];
  float s = khop_tile(Tmix, nsT, b, m0, wave, lm, lq, tid, red);
  int oc = tid >> 4, orr = tid & 15;
  size_t oidx = ((size_t)b * 16 + oc) * N_ + m0 + orr;
  if (oc < 14) {
    in28s[orr][oc] = nsT[oidx];
    in28s[orr][14 + oc] = f2h(s);
  } else if (oc == 14) {
    in28s[orr][28] = (_Float16)0.f;
    in28s[orr][29] = (_Float16)0.f;
  } else {
    in28s[orr][30] = (_Float16)0.f;
    in28s[orr][31] = (_Float16)0.f;
  }
  __syncthreads();
  f16x8 afrag = *(const f16x8*)(&in28s[lm][lq * 8]);
#pragma unroll
  for (int nt = 0; nt < 4; ++nt) {
    int n0 = wave * 64 + nt * 16;
    f16x8 bfrag = *(const f16x8*)(Wint + (size_t)(n0 + lm) * 32 + lq * 8);
    f32x4 c4 = {0.f, 0.f, 0.f, 0.f};
    c4 = __builtin_amdgcn_mfma_f32_16x16x32_f16(afrag, bfrag, c4, 0, 0, 0);
    float bv = bin[n0 + lm];
#pragma unroll
    for (int rg = 0; rg < 4; ++rg) {
      int rw = lq * 4 + rg;
      float val = c4[rg] + bv;
      size_t o = ((size_t)(b * N_ + m0 + rw)) * 256 + n0 + lm;
      x0[o] = val;
      xh[o] = f2h(val);
    }
  }
}

// FALLBACK PATH: single hop, acc (+)= w * hop
__global__ __launch_bounds__(256) void khop_kernel(const _Float16* __restrict__ Tb,
    const _Float16* __restrict__ HinT, _Float16* __restrict__ HoutT,
    float* __restrict__ accT, float w, int first) {
  int b = blockIdx.y, m0 = blockIdx.x * 16;
  int tid = threadIdx.x;
  int wave = tid >> 6, lane = tid & 63;
  int lm = lane & 15, lq = lane >> 4;
  __shared__ float red[4][16][17];
  float s = khop_tile(Tb, HinT, b, m0, wave, lm, lq, tid, red);
  int c = tid >> 4, r = tid & 15;
  size_t o = ((size_t)b * 16 + c) * N_ + m0 + r;
  if (HoutT) HoutT[o] = f2h(s);
  if (first) accT[o] = w * s; else accT[o] += w * s;
}

// FALLBACK: hop3 + input projection
__global__ __launch_bounds__(256) void khop3_input(const _Float16* __restrict__ Tb,
    const _Float16* __restrict__ HinT, const _Float16* __restrict__ nsT,
    const float* __restrict__ accT, const _Float16* __restrict__ Wint,
    const float* __restrict__ bin, float hw2,
    float* __restrict__ x0, _Float16* __restrict__ xh) {
  int b = blockIdx.y, m0 = blockIdx.x * 16;
  int tid = threadIdx.x;
  int wave = tid >> 6, lane = tid & 63;
  int lm = lane & 15, lq = lane >> 4;
  __shared__ float red[4][16][17];
  __shared__ _Float16 in28s[16][32];
  float s = khop_tile(Tb, HinT, b, m0, wave, lm, lq, tid, red);
  int oc = tid >> 4, orr = tid & 15;
  size_t oidx = ((size_t)b * 16 + oc) * N_ + m0 + orr;
  if (oc < 14) {
    float atot = accT[oidx] + hw2 * s;
    in28s[orr][oc] = nsT[oidx];
    in28s[orr][14 + oc] = f2h(atot);
  } else if (oc == 14) {
    in28s[orr][28] = (_Float16)0.f;
    in28s[orr][29] = (_Float16)0.f;
  } else {
    in28s[orr][30] = (_Float16)0.f;
    in28s[orr][31] = (_Float16)0.f;
  }
  __syncthreads();
  f16x8 afrag = *(const f16x8*)(&in28s[lm][lq * 8]);
#pragma unroll
  for (int nt = 0; nt < 4; ++nt) {
    int n0 = wave * 64 + nt * 16;
    f16x8 bfrag = *(const f16x8*)(Wint + (size_t)(n0 + lm) * 32 + lq * 8);
    f32x4 c4 = {0.f, 0.f, 0.f, 0.f};
    c4 = __builtin_amdgcn_mfma_f32_16x16x32_f16(afrag, bfrag, c4, 0, 0, 0);
    float bv = bin[n0 + lm];
#pragma unroll
    for (int rg = 0; rg < 4; ++rg) {
      int rw = lq * 4 + rg;
      float val = c4[rg] + bv;
      size_t o = ((size_t)(b * N_ + m0 + rw)) * 256 + n0 + lm;
      x0[o] = val;
      xh[o] = f2h(val);
    }
  }
}

// one wave per node; software-pipelined edge gather
__global__ __launch_bounds__(256) void attn_kernel(const _Float16* __restrict__ qkv,
    const int* __restrict__ offs, const int* __restrict__ sp,
    const float* __restrict__ ebp, _Float16* __restrict__ aggh) {
  int node = blockIdx.x * 4 + (threadIdx.x >> 6);
  int lane = threadIdx.x & 63;
  int h = lane >> 3;
  f16x4 qh = *(const f16x4*)(qkv + (size_t)node * 768 + lane * 4);
  float4 q4 = {(float)qh[0], (float)qh[1], (float)qh[2], (float)qh[3]};
  int beg = offs[node], end = offs[node + 1];
  float mx = -3.0e38f, den = 0.f;
  float4 acc = {0.f, 0.f, 0.f, 0.f};
  f16x4 kh_n = {}, vh_n = {};
  float eb_n = 0.f;
  if (beg < end) {
    int s = sp[beg];
    const _Float16* base = qkv + (size_t)s * 768 + lane * 4;
    kh_n = *(const f16x4*)(base + 256);
    vh_n = *(const f16x4*)(base + 512);
    eb_n = ebp[(size_t)beg * 8 + h];
  }
  for (int j = beg; j < end; ++j) {
    f16x4 kh = kh_n, vh = vh_n;
    float ebv = eb_n;
    if (j + 1 < end) {
      int s2 = sp[j + 1];
      const _Float16* b2 = qkv + (size_t)s2 * 768 + lane * 4;
      kh_n = *(const f16x4*)(b2 + 256);
      vh_n = *(const f16x4*)(b2 + 512);
      eb_n = ebp[(size_t)(j + 1) * 8 + h];
    }
    float p = q4.x * (float)kh[0] + q4.y * (float)kh[1]
            + q4.z * (float)kh[2] + q4.w * (float)kh[3];
    p += __shfl_xor(p, 1);
    p += __shfl_xor(p, 2);
    p += __shfl_xor(p, 4);
    float score = p * 0.17677669529663687f + ebv;
    float nm = fmaxf(mx, score);
    float sc = __expf(mx - nm);
    float w = __expf(score - nm);
    den = den * sc + w;
    acc.x = acc.x * sc + w * (float)vh[0];
    acc.y = acc.y * sc + w * (float)vh[1];
    acc.z = acc.z * sc + w * (float)vh[2];
    acc.w = acc.w * sc + w * (float)vh[3];
    mx = nm;
  }
  float inv = den > 0.f ? 1.f / den : 0.f;
  f16x4 o;
  o[0] = f2h(acc.x * inv);
  o[1] = f2h(acc.y * inv);
  o[2] = f2h(acc.z * inv);
  o[3] = f2h(acc.w * inv);
  *(f16x4*)(aggh + (size_t)node * DM_ + lane * 4) = o;
}

// O-proj + residual + LN1 (M-tile 16, grid 512 blocks)
__global__ __launch_bounds__(256) void oproj_ln1(const _Float16* __restrict__ A,
    const _Float16* __restrict__ Wt, const float* __restrict__ bias,
    const float* __restrict__ res, const float* __restrict__ g,
    const float* __restrict__ bb, float* __restrict__ yF,
    _Float16* __restrict__ yH) {
  int m0 = blockIdx.x * 16;
  int wave = threadIdx.x >> 6, lane = threadIdx.x & 63;
  int lm = lane & 15, lq = lane >> 4;
  int n0 = wave * 64;
  f32x4 acc[4] = {};
  const _Float16* Ap = A + (size_t)(m0 + lm) * 256 + lq * 8;
  const _Float16* Bp = Wt + (size_t)(n0 + lm) * 256 + lq * 8;
  for (int k = 0; k < 256; k += 32) {
    f16x8 a0 = *(const f16x8*)(Ap + k);
#pragma unroll
    for (int nt = 0; nt < 4; ++nt) {
      f16x8 bf = *(const f16x8*)(Bp + nt * 16 * 256 + k);
      acc[nt] = __builtin_amdgcn_mfma_f32_16x16x32_f16(a0, bf, acc[nt], 0, 0, 0);
    }
  }
  float val[4][4];
  float rsum[4] = {}, rsq[4] = {};
#pragma unroll
  for (int nt = 0; nt < 4; ++nt) {
    int col = n0 + nt * 16 + lm;
    float bv = bias[col];
#pragma unroll
    for (int rg = 0; rg < 4; ++rg) {
      int row = m0 + lq * 4 + rg;
      float x = acc[nt][rg] + bv + res[(size_t)row * 256 + col];
      val[nt][rg] = x;
      rsum[rg] += x;
      rsq[rg] += x * x;
    }
  }
#pragma unroll
  for (int rg = 0; rg < 4; ++rg)
    for (int off = 1; off < 16; off <<= 1) {
      rsum[rg] += __shfl_xor(rsum[rg], off);
      rsq[rg] += __shfl_xor(rsq[rg], off);
    }
  __shared__ float redS[16][4], redQ[16][4];
  if (lm == 0) {
#pragma unroll
    for (int rg = 0; rg < 4; ++rg) {
      int r = lq * 4 + rg;
      redS[r][wave] = rsum[rg];
      redQ[r][wave] = rsq[rg];
    }
  }
  __syncthreads();
#pragma unroll
  for (int rg = 0; rg < 4; ++rg) {
    int r = lq * 4 + rg;
    float tS = redS[r][0] + redS[r][1] + redS[r][2] + redS[r][3];
    float tQ = redQ[r][0] + redQ[r][1] + redQ[r][2] + redQ[r][3];
    float mu = tS * (1.f / 256.f);
    float var = tQ * (1.f / 256.f) - mu * mu;
    float rs = rsqrtf(var + 1e-5f);
    int row = m0 + r;
#pragma unroll
    for (int nt = 0; nt < 4; ++nt) {
      int col = n0 + nt * 16 + lm;
      float y = g[col] * (val[nt][rg] - mu) * rs + bb[col];
      size_t o = (size_t)row * 256 + col;
      yF[o] = y;
      yH[o] = f2h(y);
    }
  }
}

// fused FFN with LDS overlay: h (phase1) shares LDS with xs/whs/part (phase3)
struct FfnS2 {
  float xs[32][261];
  float whs[3072];
  float part[32][193];
};
union FfnU {
  _Float16 hs[32][1040];
  FfnS2 s2;
};

__global__ __launch_bounds__(512) void ffn_fused(const _Float16* __restrict__ A,
    const _Float16* __restrict__ Wf1t, const float* __restrict__ bf1,
    const _Float16* __restrict__ Wf2t, const float* __restrict__ bf2,
    const float* __restrict__ res, const float* __restrict__ g,
    const float* __restrict__ bb, const float* __restrict__ Wh,
    const float* __restrict__ bh, const float* __restrict__ pm,
    const float* __restrict__ qm, float* __restrict__ v,
    float* __restrict__ th, float* __restrict__ m) {
  int m0 = blockIdx.x * 32;
  int tid = threadIdx.x;
  int wave = tid >> 6, lane = tid & 63;
  int lm = lane & 15, lq = lane >> 4;
  __shared__ FfnU u;
  __shared__ float redS[32][8], redQ[32][8];
  // phase 1: h[32][1024] = relu(x @ Wf1 + bf1)
  {
    int n0 = wave * 128;
    f32x4 acc1[2][8] = {};
    const _Float16* Ap = A + (size_t)(m0 + lm) * 256 + lq * 8;
    const _Float16* Bp = Wf1t + (size_t)(n0 + lm) * 256 + lq * 8;
    for (int k = 0; k < 256; k += 32) {
      f16x8 a0 = *(const f16x8*)(Ap + k);
      f16x8 a1 = *(const f16x8*)(Ap + 16 * 256 + k);
#pragma unroll
      for (int nt = 0; nt < 8; ++nt) {
        f16x8 bf = *(const f16x8*)(Bp + nt * 16 * 256 + k);
        acc1[0][nt] = __builtin_amdgcn_mfma_f32_16x16x32_f16(a0, bf, acc1[0][nt], 0, 0, 0);
        acc1[1][nt] = __builtin_amdgcn_mfma_f32_16x16x32_f16(a1, bf, acc1[1][nt], 0, 0, 0);
      }
    }
#pragma unroll
    for (int mt = 0; mt < 2; ++mt)
#pragma unroll
      for (int nt = 0; nt < 8; ++nt) {
        int col = n0 + nt * 16 + lm;
        float bv = bf1[col];
#pragma unroll
        for (int rg = 0; rg < 4; ++rg) {
          int rloc = mt * 16 + lq * 4 + rg;
          u.hs[rloc][col] = f2h(fmaxf(acc1[mt][nt][rg] + bv, 0.f));
        }
      }
  }
  __syncthreads();
  // phase 2: y[32][256] = h @ Wf2 + bf2 + res, LN  (reads u.hs)
  float val[2][2][4];
  float rsum[2][4] = {}, rsq[2][4] = {};
  {
    int n0 = wave * 32;
    f32x4 acc2[2][2] = {};
    const _Float16* Bp = Wf2t + (size_t)(n0 + lm) * 1024 + lq * 8;
    for (int k = 0; k < 1024; k += 32) {
      f16x8 a0 = *(const f16x8*)(&u.hs[lm][k + lq * 8]);
      f16x8 a1 = *(const f16x8*)(&u.hs[16 + lm][k + lq * 8]);
      f16x8 b0 = *(const f16x8*)(Bp + k);
      f16x8 b1 = *(const f16x8*)(Bp + 16 * 1024 + k);
      acc2[0][0] = __builtin_amdgcn_mfma_f32_16x16x32_f16(a0, b0, acc2[0][0], 0, 0, 0);
      acc2[0][1] = __builtin_amdgcn_mfma_f32_16x16x32_f16(a0, b1, acc2[0][1], 0, 0, 0);
      acc2[1][0] = __builtin_amdgcn_mfma_f32_16x16x32_f16(a1, b0, acc2[1][0], 0, 0, 0);
      acc2[1][1] = __builtin_amdgcn_mfma_f32_16x16x32_f16(a1, b1, acc2[1][1], 0, 0, 0);
    }
#pragma unroll
    for (int mt = 0; mt < 2; ++mt)
#pragma unroll
      for (int nt = 0; nt < 2; ++nt) {
        int col = n0 + nt * 16 + lm;
        float bv = bf2[col];
#pragma unroll
        for (int rg = 0; rg < 4; ++rg) {
          int row = m0 + mt * 16 + lq * 4 + rg;
          float x = acc2[mt][nt][rg] + bv + res[(size_t)row * 256 + col];
          val[mt][nt][rg] = x;
          rsum[mt][rg] += x;
          rsq[mt][rg] += x * x;
        }
      }
  }
#pragma unroll
  for (int mt = 0; mt < 2; ++mt)
#pragma unroll
    for (int rg = 0; rg < 4; ++rg)
      for (int off = 1; off < 16; off <<= 1) {
        rsum[mt][rg] += __shfl_xor(rsum[mt][rg], off);
        rsq[mt][rg] += __shfl_xor(rsq[mt][rg], off);
      }
  if (lm == 0) {
#pragma unroll
    for (int mt = 0; mt < 2; ++mt)
#pragma unroll
      for (int rg = 0; rg < 4; ++rg) {
        int r = mt * 16 + lq * 4 + rg;
        redS[r][wave] = rsum[mt][rg];
        redQ[r][wave] = rsq[mt][rg];
      }
  }
  __syncthreads();  // all hs reads done; s2 region now safe to write
  for (int i = tid; i < 3072; i += 512) u.s2.whs[i] = Wh[i];
#pragma unroll
  for (int mt = 0; mt < 2; ++mt)
#pragma unroll
    for (int rg = 0; rg < 4; ++rg) {
      int r = mt * 16 + lq * 4 + rg;
      float tS = 0.f, tQ = 0.f;
#pragma unroll
      for (int w = 0; w < 8; ++w) { tS += redS[r][w]; tQ += redQ[r][w]; }
      float mu = tS * (1.f / 256.f);
      float var = tQ * (1.f / 256.f) - mu * mu;
      float rs = rsqrtf(var + 1e-5f);
#pragma unroll
      for (int nt = 0; nt < 2; ++nt) {
        int col = wave * 32 + nt * 16 + lm;
        u.s2.xs[r][col] = g[col] * (val[mt][nt][rg] - mu) * rs + bb[col];
      }
    }
  __syncthreads();
  // heads: 12 dots per row over 256 cols (16 groups x 16 cols)
  {
    int rw = tid & 31, grp = tid >> 5;
    float pa[12] = {};
    for (int c = 0; c < 16; ++c) {
      int col = grp * 16 + c;
      float xv = u.s2.xs[rw][col];
#pragma unroll
      for (int o = 0; o < 12; ++o) pa[o] += xv * u.s2.whs[col * 12 + o];
    }
#pragma unroll
    for (int o = 0; o < 12; ++o) u.s2.part[rw][grp * 12 + o] = pa[o];
  }
  __syncthreads();
  if (tid < 32) {
    int node = m0 + tid;
    float tot[12];
#pragma unroll
    for (int o = 0; o < 12; ++o) {
      float s = bh[o];
#pragma unroll
      for (int grp = 0; grp < 16; ++grp) s += u.s2.part[tid][grp * 12 + o];
      tot[o] = s;
    }
    th[node] += tot[0] * pm[node];
    v[node] += tot[1] * qm[node];
#pragma unroll
    for (int d = 0; d < 10; ++d) m[(size_t)node * 10 + d] = tot[2 + d];
  }
}

__global__ void out_kernel(const float* __restrict__ v, const float* __restrict__ th,
                           float* __restrict__ out) {
  int t = blockIdx.x * blockDim.x + threadIdx.x;
  if (t >= BN_) return;
  out[2 * t] = v[t];
  out[2 * t + 1] = th[t];
}

// ---------------- launcher ----------------

extern "C" void kernel_launch(void* const* d_in, const int* in_sizes, int n_in,
                              void* d_out, int out_size, void* d_ws, size_t ws_size,
                              hipStream_t stream) {
  const int* bus = (const int*)d_in[0];
  const int* ei = (const int*)d_in[1];
  const float* G = (const float*)d_in[2];
  const float* Bm = (const float*)d_in[3];
  const float* P = (const float*)d_in[4];
  const float* Q = (const float*)d_in[5];
  const float* V0 = (const float*)d_in[6];
  const float* efeat = (const float*)d_in[7];
  const float* Win = (const float*)d_in[8];
  const float* bin = (const float*)d_in[9];
  const float* Wq = (const float*)d_in[10];
  const float* bq = (const float*)d_in[11];
  const float* Wk = (const float*)d_in[12];
  const float* bk = (const float*)d_in[13];
  const float* Wv = (const float*)d_in[14];
  const float* bv = (const float*)d_in[15];
  const float* Wo = (const float*)d_in[16];
  const float* bo = (const float*)d_in[17];
  const float* We = (const float*)d_in[18];
  const float* be = (const float*)d_in[19];
  const float* g1 = (const float*)d_in[20];
  const float* b1 = (const float*)d_in[21];
  const float* g2 = (const float*)d_in[22];
  const float* b2 = (const float*)d_in[23];
  const float* Wf1 = (const float*)d_in[24];
  const float* bf1 = (const float*)d_in[25];
  const float* Wf2 = (const float*)d_in[26];
  const float* bf2 = (const float*)d_in[27];
  const float* Wth = (const float*)d_in[28];
  const float* bth = (const float*)d_in[29];
  const float* Wvh = (const float*)d_in[30];
  const float* bvh = (const float*)d_in[31];
  const float* Wm = (const float*)d_in[32];
  const float* bm = (const float*)d_in[33];
  float* out = (float*)d_out;

  char* p = (char*)d_ws;
  auto alloc = [&](size_t bytes) -> void* {
    void* r = (void*)p;
    p += (bytes + 255) & ~(size_t)255;
    return r;
  };
  _Float16* Tb = (_Float16*)alloc((size_t)BN_ * N_ * 2);     // 33.5 MB
  _Float16* nsT = (_Float16*)alloc((size_t)B_ * 16 * N_ * 2);
  _Float16* H1 = (_Float16*)alloc((size_t)B_ * 16 * N_ * 2);
  _Float16* H2 = (_Float16*)alloc((size_t)B_ * 16 * N_ * 2);
  float* accT = (float*)alloc((size_t)B_ * 16 * N_ * 4);
  _Float16* qkvh = (_Float16*)alloc((size_t)BN_ * 768 * 2);
  float* x0 = (float*)alloc((size_t)BN_ * 256 * 4);
  float* x1 = (float*)alloc((size_t)BN_ * 256 * 4);
  _Float16* xhA = (_Float16*)alloc((size_t)BN_ * 256 * 2);
  _Float16* xhB = (_Float16*)alloc((size_t)BN_ * 256 * 2);
  float* eb = (float*)alloc((size_t)BE_ * 8 * 4);
  float* ebp = (float*)alloc((size_t)BE_ * 8 * 4);
  int* srcf = (int*)alloc((size_t)BE_ * 4);
  int* dstf = (int*)alloc((size_t)BE_ * 4);
  int* sp = (int*)alloc((size_t)BE_ * 4);
  int* counts = (int*)alloc((size_t)BN_ * 4);
  int* offs = (int*)alloc((size_t)(BN_ + 1) * 4);
  int* cursor = (int*)alloc((size_t)BN_ * 4);
  int* perm = (int*)alloc((size_t)BE_ * 4);
  _Float16* Wqkvt = (_Float16*)alloc(768 * 256 * 2);
  _Float16* Wot = (_Float16*)alloc(256 * 256 * 2);
  _Float16* Wf1t = (_Float16*)alloc(1024 * 256 * 2);
  _Float16* Wf2t = (_Float16*)alloc(256 * 1024 * 2);
  _Float16* Wint = (_Float16*)alloc(256 * 32 * 2);
  float* Wheads = (float*)alloc(30 * 3072 * 4);
  float* bheads = (float*)alloc(30 * 12 * 4);
  float* bqkv = (float*)alloc(768 * 4);
  float* v = (float*)alloc((size_t)BN_ * 4);
  float* th = (float*)alloc((size_t)BN_ * 4);
  float* pm = (float*)alloc((size_t)BN_ * 4);
  float* qm = (float*)alloc((size_t)BN_ * 4);
  float* m = (float*)alloc((size_t)BN_ * 10 * 4);

  size_t nn2 = (size_t)B_ * N_ * N_ * 2;  // 33.5 MB
  size_t used = (size_t)(p - (char*)d_ws);
  bool tmix_ok = (used + 3 * (nn2 + 256) <= ws_size);
  _Float16 *Tt = nullptr, *T2 = nullptr, *Tmix = nullptr;
  if (tmix_ok) {
    Tt = (_Float16*)alloc(nn2);
    T2 = (_Float16*)alloc(nn2);
    Tmix = (_Float16*)alloc(nn2);
  }
  used = (size_t)(p - (char*)d_ws);
  bool f16gb = (used + 2 * (nn2 + 256) <= ws_size);
  _Float16 *Gh = nullptr, *Bh = nullptr;
  if (f16gb) {
    Gh = (_Float16*)alloc(nn2);
    Bh = (_Float16*)alloc(nn2);
  }

  double hwd[3], z = 0.0;
  for (int i = 0; i < 3; ++i) {
    hwd[i] = exp(-((double)(i + 1) * (i + 1)) / (2.0 * 1.5 * 1.5));
    z += hwd[i];
  }
  float hw0 = (float)(hwd[0] / z), hw1 = (float)(hwd[1] / z), hw2 = (float)(hwd[2] / z);

  init_state<<<32, 256, 0, stream>>>(bus, V0, v, th, m, pm, qm, counts);
  build_T_cast<<<8192, 256, 0, stream>>>(G, Bm, Tb, Gh, Bh);
  if (tmix_ok) {
    transpose16<<<dim3(32, 32, 4), 256, 0, stream>>>(Tb, Tt);
    // T2 = T @ T
    gemm_bat2<<<dim3(16, 16, 4), 256, 0, stream>>>(Tb, Tt, T2,
        (const _Float16*)nullptr, (const _Float16*)nullptr, 0.f, 0.f, 0.f);
    // Tmix = hw0*T + hw1*T2 + hw2*(T2 @ T)
    gemm_bat2<<<dim3(16, 16, 4), 256, 0, stream>>>(T2, Tt, Tmix, Tb, T2,
                                                   hw0, hw1, hw2);
  }
  edge_prep<<<BE_ / 256, 256, 0, stream>>>(ei, efeat, We, be, eb, srcf, dstf, counts);
  scan_kernel<<<1, 256, 0, stream>>>(counts, offs, cursor);
  scatter_kernel<<<BE_ / 256, 256, 0, stream>>>(dstf, cursor, perm);
  edge_reorder<<<BE_ / 256, 256, 0, stream>>>(perm, srcf, eb, sp, ebp);
  prep_weights<<<(887912 + 255) / 256, 256, 0, stream>>>(
      Wq, bq, Wk, bk, Wv, bv, Wo, Wf1, Wf2, Wth, bth, Wvh, bvh, Wm, bm, Win,
      Wqkvt, bqkv, Wot, Wf1t, Wf2t, Wheads, bheads, Wint);

  for (int k = 0; k < 30; ++k) {
    if (f16gb)
      matvec_ns_f16<<<dim3(128, 4), 256, 0, stream>>>(Gh, Bh, v, th, P, Q, pm, qm,
                                                      m, nsT);
    else
      matvec_ns_f32<<<dim3(128, 4), 256, 0, stream>>>(G, Bm, v, th, P, Q, pm, qm,
                                                      m, nsT);
    if (tmix_ok) {
      khop_mix_input<<<dim3(128, 4), 256, 0, stream>>>(Tmix, nsT, Wint, bin,
                                                       x0, xhA);
    } else {
      khop_kernel<<<dim3(128, 4), 256, 0, stream>>>(Tb, nsT, H1, accT, hw0, 1);
      khop_kernel<<<dim3(128, 4), 256, 0, stream>>>(Tb, H1, H2, accT, hw1, 0);
      khop3_input<<<dim3(128, 4), 256, 0, stream>>>(Tb, H2, nsT, accT, Wint, bin,
                                                    hw2, x0, xhA);
    }
    qkv_ldst<<<dim3(64, 6), 256, 0, stream>>>(xhA, Wqkvt, bqkv, qkvh);
    attn_kernel<<<2048, 256, 0, stream>>>(qkvh, offs, sp, ebp, xhB);
    oproj_ln1<<<512, 256, 0, stream>>>(xhB, Wot, bo, x0, g1, b1, x1, xhA);
    ffn_fused<<<256, 512, 0, stream>>>(xhA, Wf1t, bf1, Wf2t, bf2, x1, g2, b2,
                                       Wheads + k * 3072, bheads + k * 12,
                                       pm, qm, v, th, m);
  }
  out_kernel<<<32, 256, 0, stream>>>(v, th, out);
}